// Round 3
// baseline (446.295 us; speedup 1.0000x reference)
//
#include <hip/hip_runtime.h>

// ---------------------------------------------------------------------------
// Sliding-window GQA attention block.
// R6 = R5 with the v_permlane32_swap_b32 orientation FIXED (R5 never ran:
// container infra failure; audit found dst/src swapped).
// Semantics (gfx950): v_permlane32_swap_b32 vdst, vsrc swaps
//   vdst.lanes[32:63] <-> vsrc.lanes[0:31]  (analog of permlane16_swap's
//   "odd rows of dst <-> even rows of src").
// With xa = key-group g_e word, xb = group g_o word:
//   swap(dst=xa, src=xb):
//     xa' = (h0: xa(h0), h1: xb(h0))  -> PV-A word j0..3 (source half 0)
//     xb' = (h0: xa(h1), h1: xb(h1))  -> PV-A word j4..7 (source half 1)
// Attention: swapped-operand 32x32x16 QK^T (lane owns one query column),
// in-register softmax, cvt_pk_bf16 + permlane32_swap for P->PV fragments
// (no Ps LDS), T14 async-STAGE split for K/V, T5 setprio. O-proj on the
// R4-verified 8-phase 256x256 template.
// ---------------------------------------------------------------------------

typedef __bf16 bf16x8 __attribute__((ext_vector_type(8)));
typedef float f32x4 __attribute__((ext_vector_type(4)));
typedef float f32x16 __attribute__((ext_vector_type(16)));
typedef int v8i __attribute__((ext_vector_type(8)));
typedef unsigned int u32x4 __attribute__((ext_vector_type(4)));

__device__ __forceinline__ unsigned short f2bf(float f) {
  unsigned int u = __float_as_uint(f);
  u += 0x7fffu + ((u >> 16) & 1u);   // RNE
  return (unsigned short)(u >> 16);
}

__device__ __forceinline__ f32x4 mfma16(bf16x8 a, bf16x8 b, f32x4 c) {
  return __builtin_amdgcn_mfma_f32_16x16x32_bf16(a, b, c, 0, 0, 0);
}

__device__ __forceinline__ f32x16 mfma32(bf16x8 a, bf16x8 b, f32x16 c) {
  return __builtin_amdgcn_mfma_f32_32x32x16_bf16(a, b, c, 0, 0, 0);
}

// pack two f32 -> two bf16 in one u32 (RNE); no builtin on gfx950 (m240)
__device__ __forceinline__ unsigned int cvtpk_bf16(float lo, float hi) {
  unsigned int r;
  asm volatile("v_cvt_pk_bf16_f32 %0, %1, %2" : "=v"(r) : "v"(lo), "v"(hi));
  return r;
}

// async global->LDS, 16B per lane, deposits at wave-uniform base + lane*16
__device__ __forceinline__ void async16(void* lds, const void* g) {
  __builtin_amdgcn_global_load_lds(
      (__attribute__((address_space(1))) unsigned int*)g,
      (__attribute__((address_space(3))) unsigned int*)lds, 16, 0, 0);
}

// --------------------------- conversion kernels ----------------------------

// hidden f32 -> bf16 (for V-proj) AND fp8 e4m3 (for QK-proj)
__global__ __launch_bounds__(256) void convert_h_kernel(
    const float* __restrict__ src, unsigned short* __restrict__ dbf,
    unsigned char* __restrict__ d8, int n) {
  int i = (blockIdx.x * 256 + threadIdx.x) * 4;
  if (i < n) {
    float4 f = *(const float4*)(src + i);
    ushort4 o;
    o.x = f2bf(f.x); o.y = f2bf(f.y); o.z = f2bf(f.z); o.w = f2bf(f.w);
    *(ushort4*)(dbf + i) = o;
    int p = __builtin_amdgcn_cvt_pk_fp8_f32(f.x, f.y, 0, 0);
    p = __builtin_amdgcn_cvt_pk_fp8_f32(f.z, f.w, p, 1);
    *(unsigned int*)(d8 + i) = p;
  }
}

// src f32 [K][N] row-major  ->  dst bf16 [N][K] row-major (transposed)
__global__ __launch_bounds__(256) void transpose_convert_kernel(
    const float* __restrict__ src, unsigned short* __restrict__ dst,
    int K, int N) {
  __shared__ unsigned short T[64 * 72];
  int kb = blockIdx.y * 64, nb = blockIdx.x * 64;
  int t = threadIdx.x;
  for (int u = t; u < 1024; u += 256) {
    int r = u >> 4, s = u & 15;
    float4 f = *(const float4*)(src + (size_t)(kb + r) * N + nb + s * 4);
    ushort4 o;
    o.x = f2bf(f.x); o.y = f2bf(f.y); o.z = f2bf(f.z); o.w = f2bf(f.w);
    *(ushort4*)&T[r * 72 + s * 4] = o;
  }
  __syncthreads();
  for (int u = t; u < 1024; u += 256) {
    int orow = u >> 4, s = u & 15;
    ushort4 o;
    o.x = T[(s * 4 + 0) * 72 + orow];
    o.y = T[(s * 4 + 1) * 72 + orow];
    o.z = T[(s * 4 + 2) * 72 + orow];
    o.w = T[(s * 4 + 3) * 72 + orow];
    *(ushort4*)(dst + (size_t)(nb + orow) * K + kb + s * 4) = o;
  }
}

// src f32 [K][N] row-major -> dst fp8 e4m3 [N][K] (transposed)
__global__ __launch_bounds__(256) void transpose_convert_fp8_kernel(
    const float* __restrict__ src, unsigned char* __restrict__ dst,
    int K, int N) {
  __shared__ unsigned short T[64 * 72];
  int kb = blockIdx.y * 64, nb = blockIdx.x * 64;
  int t = threadIdx.x;
  for (int u = t; u < 1024; u += 256) {
    int r = u >> 4, s = u & 15;
    float4 f = *(const float4*)(src + (size_t)(kb + r) * N + nb + s * 4);
    ushort4 o;
    o.x = f2bf(f.x); o.y = f2bf(f.y); o.z = f2bf(f.z); o.w = f2bf(f.w);
    *(ushort4*)&T[r * 72 + s * 4] = o;
  }
  __syncthreads();
  for (int u = t; u < 1024; u += 256) {
    int orow = u >> 4, s = u & 15;
    float f0 = __uint_as_float((unsigned int)T[(s * 4 + 0) * 72 + orow] << 16);
    float f1 = __uint_as_float((unsigned int)T[(s * 4 + 1) * 72 + orow] << 16);
    float f2 = __uint_as_float((unsigned int)T[(s * 4 + 2) * 72 + orow] << 16);
    float f3 = __uint_as_float((unsigned int)T[(s * 4 + 3) * 72 + orow] << 16);
    int p = __builtin_amdgcn_cvt_pk_fp8_f32(f0, f1, 0, 0);
    p = __builtin_amdgcn_cvt_pk_fp8_f32(f2, f3, p, 1);
    *(unsigned int*)&dst[(size_t)(nb + orow) * K + kb + s * 4] = p;
  }
}

// V slice of QKV [8192 rows][cols 2560..3071] -> VTg [512][8192] bf16.
__global__ __launch_bounds__(256) void vtrans_kernel(
    const unsigned short* __restrict__ QKV, unsigned short* __restrict__ VTg) {
  int flat = blockIdx.x * 256 + threadIdx.x;
  int c = flat & 511;
  int s0 = (flat >> 9) * 8;
  unsigned short tmp[8];
  #pragma unroll
  for (int j = 0; j < 8; ++j)
    tmp[j] = QKV[(size_t)(s0 + j) * 3072 + 2560 + c];
  *(uint4*)&VTg[(size_t)c * 8192 + s0] = *(uint4*)tmp;
}

// ---------------------------- bf16 GEMM (V-proj) ---------------------------
// C[M,:] (ldc) = A[M,K] * BT[N,K]^T ; m97 structure, 128x128 tile, BK=32.

template <bool F32OUT>
__global__ __launch_bounds__(256) void gemm_bt_kernel(
    const unsigned short* __restrict__ A, const unsigned short* __restrict__ BT,
    void* __restrict__ Cp, int M, int ldc, int K) {
  __shared__ unsigned short As[128 * 32];
  __shared__ unsigned short Bs[128 * 32];
  int mb = blockIdx.y * 128, nb = blockIdx.x * 128;
  int tid = threadIdx.x;
  int lane = tid & 63, wv = tid >> 6;
  int wrow = wv >> 1, wcol = wv & 1;
  int lr = lane >> 2, ls = lane & 3;
  int fr = lane & 15, fg = lane >> 4;
  f32x4 acc[4][4] = {};
  for (int k0 = 0; k0 < K; k0 += 32) {
    __syncthreads();
    #pragma unroll
    for (int r = 0; r < 2; ++r) {
      int s = wv * 2 + r;
      async16(&As[s * 512], &A[(size_t)(mb + s * 16 + lr) * K + k0 + ls * 8]);
      async16(&Bs[s * 512], &BT[(size_t)(nb + s * 16 + lr) * K + k0 + ls * 8]);
    }
    __syncthreads();
    bf16x8 a[4], b[4];
    #pragma unroll
    for (int rt = 0; rt < 4; ++rt)
      a[rt] = *(const bf16x8*)&As[(wrow * 64 + rt * 16 + fr) * 32 + fg * 8];
    #pragma unroll
    for (int ct = 0; ct < 4; ++ct)
      b[ct] = *(const bf16x8*)&Bs[(wcol * 64 + ct * 16 + fr) * 32 + fg * 8];
    #pragma unroll
    for (int rt = 0; rt < 4; ++rt)
      #pragma unroll
      for (int ct = 0; ct < 4; ++ct)
        acc[rt][ct] = mfma16(a[rt], b[ct], acc[rt][ct]);
  }
  #pragma unroll
  for (int rt = 0; rt < 4; ++rt)
    #pragma unroll
    for (int ct = 0; ct < 4; ++ct)
      #pragma unroll
      for (int i = 0; i < 4; ++i) {
        int row = mb + wrow * 64 + rt * 16 + fg * 4 + i;
        int col = nb + wcol * 64 + ct * 16 + fr;
        if constexpr (F32OUT)
          ((float*)Cp)[(size_t)row * ldc + col] = acc[rt][ct][i];
        else
          ((unsigned short*)Cp)[(size_t)row * ldc + col] = f2bf(acc[rt][ct][i]);
      }
}

// ------------------- 8-phase 256x256 bf16 GEMM (O-proj) --------------------
// (unchanged from R4 — verified, dropped out of top-5)

__global__ __launch_bounds__(512, 2) void gemm8p_oproj_kernel(
    const unsigned short* __restrict__ A, const unsigned short* __restrict__ BT,
    float* __restrict__ C, int ldc, int K) {
  __shared__ unsigned char lds[131072];
  const int mb = blockIdx.y * 256, nb = blockIdx.x * 256;
  const int tid = threadIdx.x;
  const int lane = tid & 63, wv = tid >> 6;
  const int wm = wv >> 2, wn = wv & 3;       // 2 x 4 wave grid
  const int fr = lane & 15, fg = lane >> 4;
  const int xr = (fr & 4) ? 32 : 0;          // read-side swizzle XOR
  const int a_base = (wm * 128 + fr) * 128 + ((fg * 16) ^ xr);
  const int b_base = (wn * 64 + fr) * 128 + ((fg * 16) ^ xr);
  // staging: lane's pre-swizzled logical offset within its 1024B chunk
  const int lsw = (lane * 16) ^ (lane & 32);
  const int lrow = lsw >> 7, lcol = (lsw & 127) >> 1;
  const int NT = K >> 6;

  f32x4 acc[8][4] = {};
  bf16x8 aF[4][2], bF[2][2];

#define FENCE_ asm volatile("" ::: "memory")
#define BAR_ { FENCE_; __builtin_amdgcn_s_barrier(); FENCE_; }
#define LGKM0_ asm volatile("s_waitcnt lgkmcnt(0)" ::: "memory")
#define STAGE_A_(BUFI, T, HALF)                                              \
  { _Pragma("unroll")                                                        \
    for (int l = 0; l < 2; ++l) {                                            \
      int cc = wv * 2 + l;                                                   \
      int rb = (cc >> 3) * 128 + (HALF) * 64 + (cc & 7) * 8;                 \
      async16(lds + (BUFI) * 65536 + rb * 128,                               \
              A + (size_t)(mb + rb + lrow) * K + (T) * 64 + lcol);           \
    } }
#define STAGE_B_(BUFI, T, HALF)                                              \
  { _Pragma("unroll")                                                        \
    for (int l = 0; l < 2; ++l) {                                            \
      int cc = wv * 2 + l;                                                   \
      int rb = (cc >> 2) * 64 + (HALF) * 32 + (cc & 3) * 8;                  \
      async16(lds + (BUFI) * 65536 + 32768 + rb * 128,                       \
              BT + (size_t)(nb + rb + lrow) * K + (T) * 64 + lcol);          \
    } }
#define LOAD_A_(HALF)                                                        \
  { _Pragma("unroll")                                                        \
    for (int q = 0; q < 4; ++q)                                              \
      _Pragma("unroll")                                                      \
      for (int kk = 0; kk < 2; ++kk)                                         \
        aF[q][kk] =                                                          \
            *(const bf16x8*)&Ab_[a_base + ((HALF)*4 + q) * 2048 + kk * 64]; }
#define LOAD_B_(HALF)                                                        \
  { _Pragma("unroll")                                                        \
    for (int c2 = 0; c2 < 2; ++c2)                                           \
      _Pragma("unroll")                                                      \
      for (int kk = 0; kk < 2; ++kk)                                         \
        bF[c2][kk] =                                                         \
            *(const bf16x8*)&Bb_[b_base + ((HALF)*2 + c2) * 2048 + kk * 64]; }
#define MFMA_(RT0, CT0)                                                      \
  { __builtin_amdgcn_s_setprio(1);                                           \
    _Pragma("unroll")                                                        \
    for (int q = 0; q < 4; ++q)                                              \
      _Pragma("unroll")                                                      \
      for (int c2 = 0; c2 < 2; ++c2) {                                       \
        acc[(RT0) + q][(CT0) + c2] =                                         \
            mfma16(aF[q][0], bF[c2][0], acc[(RT0) + q][(CT0) + c2]);         \
        acc[(RT0) + q][(CT0) + c2] =                                         \
            mfma16(aF[q][1], bF[c2][1], acc[(RT0) + q][(CT0) + c2]);         \
      }                                                                      \
    __builtin_amdgcn_s_setprio(0); }

  // prologue: tile0 complete + tile1 {B-c0 half, A-r1 half}
  STAGE_A_(0, 0, 0); STAGE_A_(0, 0, 1); STAGE_B_(0, 0, 0); STAGE_B_(0, 0, 1);
  STAGE_B_(1, 1, 0); STAGE_A_(1, 1, 1);
  asm volatile("s_waitcnt vmcnt(4)" ::: "memory");   // tile0 landed
  BAR_;

  for (int t = 0; t < NT; ++t) {
    const int cur = t & 1, nxt = cur ^ 1;
    const unsigned char* Ab_ = lds + cur * 65536;
    const unsigned char* Bb_ = Ab_ + 32768;
    // ---- phase 1: quadrant r0 x c0 (12 ds_reads)
    LOAD_A_(0); LOAD_B_(0);
    if (t + 1 < NT) STAGE_A_(nxt, t + 1, 0);
    BAR_; LGKM0_;
    MFMA_(0, 0);
    BAR_;
    // ---- phase 2: quadrant r1 x c0 (8 ds_reads, bF reused)
    LOAD_A_(1);
    if (t + 1 < NT) STAGE_B_(nxt, t + 1, 1);
    BAR_; LGKM0_;
    MFMA_(4, 0);
    BAR_;
    // ---- phase 3: quadrant r1 x c1 (4 ds_reads, aF reused)
    LOAD_B_(1);
    if (t + 2 < NT) STAGE_B_(cur, t + 2, 0);
    BAR_; LGKM0_;
    MFMA_(4, 2);
    BAR_;
    // ---- phase 4: quadrant r0 x c1 (8 ds_reads, bF reused)
    LOAD_A_(0);
    if (t + 2 < NT) STAGE_A_(cur, t + 2, 1);
    BAR_; LGKM0_;
    MFMA_(0, 2);
    asm volatile("s_waitcnt vmcnt(4)" ::: "memory"); // tile t+1 landed
    BAR_;
  }

  #pragma unroll
  for (int rt = 0; rt < 8; ++rt)
    #pragma unroll
    for (int ct = 0; ct < 4; ++ct)
      #pragma unroll
      for (int i = 0; i < 4; ++i) {
        int row = mb + wm * 128 + rt * 16 + fg * 4 + i;
        int col = nb + wn * 64 + ct * 16 + fr;
        C[(size_t)row * ldc + col] = acc[rt][ct][i];
      }
#undef FENCE_
#undef BAR_
#undef LGKM0_
#undef STAGE_A_
#undef STAGE_B_
#undef LOAD_A_
#undef LOAD_B_
#undef MFMA_
}

// ---------------------------- fp8 GEMM (Q/K proj) --------------------------
// C bf16 = A8[M,K] * B8T[N,K]^T, unit-scale MX fp8, 16x16x128 MFMA, BK=128.

__global__ __launch_bounds__(256) void gemm_qk_fp8_kernel(
    const unsigned char* __restrict__ A8, const unsigned char* __restrict__ B8,
    unsigned short* __restrict__ C, int M, int ldc, int K) {
  __shared__ unsigned char As[128 * 144];
  __shared__ unsigned char Bs[128 * 144];
  int mb = blockIdx.y * 128, nb = blockIdx.x * 128;
  int tid = threadIdx.x;
  int lane = tid & 63, wv = tid >> 6;
  int wrow = wv >> 1, wcol = wv & 1;
  int fr = lane & 15, fg = lane >> 4;
  int srow = tid >> 1, shalf = (tid & 1) * 64;   // staging: 64B half-rows
  f32x4 acc[4][4] = {};
  for (int k0 = 0; k0 < K; k0 += 128) {
    __syncthreads();
    #pragma unroll
    for (int j = 0; j < 4; ++j) {
      *(uint4*)&As[srow * 144 + shalf + j * 16] =
          *(const uint4*)&A8[(size_t)(mb + srow) * K + k0 + shalf + j * 16];
      *(uint4*)&Bs[srow * 144 + shalf + j * 16] =
          *(const uint4*)&B8[(size_t)(nb + srow) * K + k0 + shalf + j * 16];
    }
    __syncthreads();
    v8i a[4], b[4];
    #pragma unroll
    for (int rt = 0; rt < 4; ++rt) {
      int off = (wrow * 64 + rt * 16 + fr) * 144 + fg * 32;
      ((uint4*)&a[rt])[0] = *(const uint4*)&As[off];
      ((uint4*)&a[rt])[1] = *(const uint4*)&As[off + 16];
    }
    #pragma unroll
    for (int ct = 0; ct < 4; ++ct) {
      int off = (wcol * 64 + ct * 16 + fr) * 144 + fg * 32;
      ((uint4*)&b[ct])[0] = *(const uint4*)&Bs[off];
      ((uint4*)&b[ct])[1] = *(const uint4*)&Bs[off + 16];
    }
    #pragma unroll
    for (int rt = 0; rt < 4; ++rt)
      #pragma unroll
      for (int ct = 0; ct < 4; ++ct)
        acc[rt][ct] = __builtin_amdgcn_mfma_scale_f32_16x16x128_f8f6f4(
            a[rt], b[ct], acc[rt][ct], 0, 0,
            0, 0x7F7F7F7F,   // A scales: e8m0 127 = 1.0
            0, 0x7F7F7F7F);  // B scales
  }
  #pragma unroll
  for (int rt = 0; rt < 4; ++rt)
    #pragma unroll
    for (int ct = 0; ct < 4; ++ct)
      #pragma unroll
      for (int i = 0; i < 4; ++i) {
        int row = mb + wrow * 64 + rt * 16 + fg * 4 + i;
        int col = nb + wcol * 64 + ct * 16 + fr;
        C[(size_t)row * ldc + col] = f2bf(acc[rt][ct][i]);
      }
}

// ----------------------------- attention -----------------------------------
// R6 structure: 8 waves x (4 heads x 2 q-halves); each wave owns 32 queries
// of one head. Swapped QK^T (A=K, B=Q) in 32x32x16 MFMA => score col = query
// = lane&31, so softmax is lane-local. P -> bf16 via v_cvt_pk_bf16_f32;
// PV A-fragments built with v_permlane32_swap_b32. K/V tiles double-pumped:
// next tile's global loads issued before compute, ds_write after barrier.
//
// Fragment routing (derived): lane half h, PV chunk kc needs local keys
// L..L+7, L = (kc&1)*16 + 8h. Keys L..L+3 live in half-0 lanes' group
// g = 2(kc&1)+h words; L+4..L+7 in half-1 lanes' same group. With
// xa = u[kt][2(kc&1)][w] (h=0's group) and xb = u[kt][2(kc&1)+1][w]
// (h=1's group):  v_permlane32_swap_b32 xa, xb  gives
//   xa' = (h0: xa(h0), h1: xb(h0)) = word from source-half 0  -> j0..3
//   xb' = (h0: xa(h1), h1: xb(h1)) = word from source-half 1  -> j4..7

#define SCALE_L2E 0.0112710027f   // log2(e)/128

__global__ __launch_bounds__(512, 2) void attn_kernel(
    const unsigned short* __restrict__ QKV,
    const unsigned short* __restrict__ VTg,
    unsigned short* __restrict__ O) {
  __shared__ unsigned short Ks[64 * 136];
  __shared__ unsigned short VTs[128 * 72];
  __shared__ float Ls[8 * 32];
  const int g = blockIdx.y;
  const int qs = blockIdx.x * 64;
  const int tid = threadIdx.x;
  const int lane = tid & 63, w = tid >> 6;
  const int l31 = lane & 31, hl2 = lane >> 5;
  const int hl = w & 3, qh = w >> 2;
  const int h = g * 4 + hl;
  const int kcol = 2048 + g * 128;
  const int qg = qs + qh * 32 + l31;   // this lane's query row

  // Q fragments (B-operand): col = query l31, k = kk*16 + hl2*8 + j
  bf16x8 qf[8];
  {
    const unsigned short* qrow = &QKV[(size_t)qg * 3072 + h * 128];
    #pragma unroll
    for (int kk = 0; kk < 8; ++kk)
      qf[kk] = *(const bf16x8*)&qrow[kk * 16 + hl2 * 8];
  }

  f32x16 o32[4] = {};     // dc: d = dc*32 + l31; row = (r&3)+8*(r>>2)+4*hl2
  float l_lane = 0.f;

  // staging decomposition (512 threads)
  const int skey = tid >> 4, sseg = tid & 15;   // K: 32 keys x 16 segs (+32 via it)
  const int sd = tid >> 3, sseg2 = tid & 7;     // V: 64 d x 8 segs (+64 via it)

  const int kb0 = qs >= 512 ? qs - 512 : 0;

  // prologue: stage tile kb0
  {
    uint4 kst[2], vst[2];
    #pragma unroll
    for (int it = 0; it < 2; ++it) {
      kst[it] = *(const uint4*)&QKV[(size_t)(kb0 + skey + it * 32) * 3072 + kcol + sseg * 8];
      vst[it] = *(const uint4*)&VTg[(size_t)(g * 128 + sd + it * 64) * 8192 + kb0 + sseg2 * 8];
    }
    #pragma unroll
    for (int it = 0; it < 2; ++it) {
      *(uint4*)&Ks[(skey + it * 32) * 136 + sseg * 8] = kst[it];
      *(uint4*)&VTs[(sd + it * 64) * 72 + sseg2 * 8] = vst[it];
    }
  }
  __syncthreads();

  for (int kb = kb0; kb <= qs; kb += 64) {
    const bool hasnext = (kb + 64 <= qs);
    uint4 kn[2], vn[2];
    if (hasnext) {   // T14: issue next tile's loads before compute
      #pragma unroll
      for (int it = 0; it < 2; ++it) {
        kn[it] = *(const uint4*)&QKV[(size_t)(kb + 64 + skey + it * 32) * 3072 + kcol + sseg * 8];
        vn[it] = *(const uint4*)&VTg[(size_t)(g * 128 + sd + it * 64) * 8192 + kb + 64 + sseg2 * 8];
      }
    }
    // ---- QK^T: S^T[key][query], 2 key-tiles of 32 ----
    f32x16 s32[2] = {};
    __builtin_amdgcn_s_setprio(1);
    #pragma unroll
    for (int kt = 0; kt < 2; ++kt)
      #pragma unroll
      for (int kk = 0; kk < 8; ++kk) {
        bf16x8 kf = *(const bf16x8*)&Ks[(kt * 32 + l31) * 136 + kk * 16 + hl2 * 8];
        s32[kt] = mfma32(kf, qf[kk], s32[kt]);
      }
    __builtin_amdgcn_s_setprio(0);

    // ---- softmax in-register + pack to bf16 pairs ----
    const bool edge = (kb > qs - 64) || (kb < qs - 448);
    unsigned int u[2][4][2];
    #pragma unroll
    for (int kt = 0; kt < 2; ++kt) {
      float p[16];
      #pragma unroll
      for (int r = 0; r < 16; ++r) {
        float pv = exp2f(s32[kt][r] * SCALE_L2E);
        if (edge) {
          int kg = kb + kt * 32 + (r & 3) + 8 * (r >> 2) + 4 * hl2;
          if (kg > qg || kg < qg - 511) pv = 0.f;
        }
        l_lane += pv;
        p[r] = pv;
      }
      #pragma unroll
      for (int gr = 0; gr < 4; ++gr) {
        u[kt][gr][0] = cvtpk_bf16(p[4 * gr + 0], p[4 * gr + 1]);
        u[kt][gr][1] = cvtpk_bf16(p[4 * gr + 2], p[4 * gr + 3]);
      }
    }

    // ---- build PV A-fragments via permlane32_swap ----
    bf16x8 af[4];
    #pragma unroll
    for (int kc = 0; kc < 4; ++kc) {
      const int kt = kc >> 1;
      const int gLo = 2 * (kc & 1), gHi = gLo + 1;
      unsigned int xa0 = u[kt][gLo][0], xb0 = u[kt][gHi][0];
      unsigned int xa1 = u[kt][gLo][1], xb1 = u[kt][gHi][1];
      // dst upper <-> src lower: dst = xa (g_even), src = xb (g_odd)
      asm volatile("v_permlane32_swap_b32 %0, %1" : "+v"(xa0), "+v"(xb0));
      asm volatile("v_permlane32_swap_b32 %0, %1" : "+v"(xa1), "+v"(xb1));
      u32x4 t;
      t[0] = xa0; t[1] = xa1; t[2] = xb0; t[3] = xb1;
      af[kc] = __builtin_bit_cast(bf16x8, t);
    }

    // ---- PV: o += P * V ----
    __builtin_amdgcn_s_setprio(1);
    #pragma unroll
    for (int dc = 0; dc < 4; ++dc)
      #pragma unroll
      for (int kc = 0; kc < 4; ++kc) {
        bf16x8 vf = *(const bf16x8*)&VTs[(dc * 32 + l31) * 72 + kc * 16 + hl2 * 8];
        o32[dc] = mfma32(af[kc], vf, o32[dc]);
      }
    __builtin_amdgcn_s_setprio(0);

    __syncthreads();               // all waves done reading LDS tile
    if (hasnext) {                 // T14: write next tile, then publish
      #pragma unroll
      for (int it = 0; it < 2; ++it) {
        *(uint4*)&Ks[(skey + it * 32) * 136 + sseg * 8] = kn[it];
        *(uint4*)&VTs[(sd + it * 64) * 72 + sseg2 * 8] = vn[it];
      }
      __syncthreads();
    }
  }

  // ---- normalize + write ----
  l_lane += __shfl_xor(l_lane, 32);       // other half's key-subset
  float linv = 1.f / l_lane;
  Ls[w * 32 + l31] = linv;                // per-wave, both halves write same
  asm volatile("s_waitcnt lgkmcnt(0)" ::: "memory");
  float lr[16];
  #pragma unroll
  for (int r = 0; r < 16; ++r)
    lr[r] = Ls[w * 32 + (r & 3) + 8 * (r >> 2) + 4 * hl2];
  #pragma unroll
  for (int dc = 0; dc < 4; ++dc)
    #pragma unroll
    for (int r = 0; r < 16; ++r) {
      int row = qs + qh * 32 + (r & 3) + 8 * (r >> 2) + 4 * hl2;
      O[(size_t)row * 2048 + h * 128 + dc * 32 + l31] =
          f2bf(o32[dc][r] * lr[r]);
    }
}

// ------------------------------ launcher -----------------------------------

extern "C" void kernel_launch(void* const* d_in, const int* in_sizes, int n_in,
                              void* d_out, int out_size, void* d_ws, size_t ws_size,
                              hipStream_t stream) {
  const float* h  = (const float*)d_in[0];
  const float* Wq = (const float*)d_in[1];
  const float* Wk = (const float*)d_in[2];
  const float* Wv = (const float*)d_in[3];
  const float* Wo = (const float*)d_in[4];
  float* out = (float*)d_out;
  char* ws = (char*)d_ws;
  const int S = 8192, D = 2048;
  const size_t MB = 1024 * 1024;

  // workspace (byte offsets), 101 MB peak, time-multiplexed:
  unsigned short* QKV = (unsigned short*)(ws);             // [8192][3072] bf16, 48 MB
  unsigned short* hbf = (unsigned short*)(ws + 48 * MB);   // [8192][2048] bf16, 32 MB
  unsigned short* Ab  = hbf;                               // attn out (hbf dead after V gemm)
  unsigned char*  h8  = (unsigned char*)(ws + 80 * MB);    // [8192][2048] fp8, 16 MB
  unsigned short* VTg = (unsigned short*)(ws + 80 * MB);   // [512][8192] bf16 (h8 dead)
  unsigned short* WoT = (unsigned short*)(ws + 88 * MB);   // [2048][2048] bf16 (h8 dead)
  unsigned char*  W8  = (unsigned char*)(ws + 96 * MB);    // [2560][2048] fp8, 5 MB
  unsigned short* WvT = (unsigned short*)(ws + 96 * MB);   // [512][2048] bf16 (W8 dead)

  convert_h_kernel<<<16384, 256, 0, stream>>>(h, hbf, h8, S * D);
  transpose_convert_fp8_kernel<<<dim3(32, 32), 256, 0, stream>>>(Wq, W8, D, 2048);
  transpose_convert_fp8_kernel<<<dim3(8, 32), 256, 0, stream>>>(
      Wk, W8 + (size_t)2048 * 2048, D, 512);
  gemm_qk_fp8_kernel<<<dim3(20, 64), 256, 0, stream>>>(h8, W8, QKV, S, 3072, D);

  transpose_convert_kernel<<<dim3(8, 32), 256, 0, stream>>>(Wv, WvT, D, 512);
  gemm_bt_kernel<false><<<dim3(4, 64), 256, 0, stream>>>(hbf, WvT, QKV + 2560, S, 3072, D);

  vtrans_kernel<<<2048, 256, 0, stream>>>(QKV, VTg);
  transpose_convert_kernel<<<dim3(32, 32), 256, 0, stream>>>(Wo, WoT, D, 2048);
  attn_kernel<<<dim3(128, 4), 512, 0, stream>>>(QKV, VTg, Ab);
  gemm8p_oproj_kernel<<<dim3(8, 32), 512, 0, stream>>>(Ab, WoT, out, 2048, 2048);
}

// Round 4
// 422.193 us; speedup vs baseline: 1.0571x; 1.0571x over previous
//
#include <hip/hip_runtime.h>

// ---------------------------------------------------------------------------
// Sliding-window GQA attention block.
// R7: attn keeps R6's verified in-register softmax (swapped 32x32x16 QK^T,
// cvt_pk_bf16 + permlane32_swap — 0 bank conflicts, correct numerics) but
// fixes R6's regression: +47MB of scratch writeback from the register-held
// T14 prefetch (WRITE_SIZE 32.7->79.9 MB, MfmaUtil 14%). K/V staging now
// uses global_load_lds into double-buffered LINEAR LDS tiles with an XOR
// swizzle (byte col ^= (row&7)<<4) applied to the pre-swizzled global
// source AND the ds_read address (both-sides-or-neither). Zero staging
// registers, one barrier per tile (its implicit vmcnt(0) drains the stage
// issued at iteration start, hidden under the full compute phase).
// O-proj stays on the R4-verified 8-phase 256x256 template.
// ---------------------------------------------------------------------------

typedef __bf16 bf16x8 __attribute__((ext_vector_type(8)));
typedef float f32x4 __attribute__((ext_vector_type(4)));
typedef float f32x16 __attribute__((ext_vector_type(16)));
typedef int v8i __attribute__((ext_vector_type(8)));
typedef unsigned int u32x4 __attribute__((ext_vector_type(4)));

__device__ __forceinline__ unsigned short f2bf(float f) {
  unsigned int u = __float_as_uint(f);
  u += 0x7fffu + ((u >> 16) & 1u);   // RNE
  return (unsigned short)(u >> 16);
}

__device__ __forceinline__ f32x4 mfma16(bf16x8 a, bf16x8 b, f32x4 c) {
  return __builtin_amdgcn_mfma_f32_16x16x32_bf16(a, b, c, 0, 0, 0);
}

__device__ __forceinline__ f32x16 mfma32(bf16x8 a, bf16x8 b, f32x16 c) {
  return __builtin_amdgcn_mfma_f32_32x32x16_bf16(a, b, c, 0, 0, 0);
}

// pack two f32 -> two bf16 in one u32 (RNE); no builtin on gfx950 (m240)
__device__ __forceinline__ unsigned int cvtpk_bf16(float lo, float hi) {
  unsigned int r;
  asm volatile("v_cvt_pk_bf16_f32 %0, %1, %2" : "=v"(r) : "v"(lo), "v"(hi));
  return r;
}

// async global->LDS, 16B per lane, deposits at wave-uniform base + lane*16
__device__ __forceinline__ void async16(void* lds, const void* g) {
  __builtin_amdgcn_global_load_lds(
      (__attribute__((address_space(1))) unsigned int*)g,
      (__attribute__((address_space(3))) unsigned int*)lds, 16, 0, 0);
}

// --------------------------- conversion kernels ----------------------------

// hidden f32 -> bf16 (for V-proj) AND fp8 e4m3 (for QK-proj)
__global__ __launch_bounds__(256) void convert_h_kernel(
    const float* __restrict__ src, unsigned short* __restrict__ dbf,
    unsigned char* __restrict__ d8, int n) {
  int i = (blockIdx.x * 256 + threadIdx.x) * 4;
  if (i < n) {
    float4 f = *(const float4*)(src + i);
    ushort4 o;
    o.x = f2bf(f.x); o.y = f2bf(f.y); o.z = f2bf(f.z); o.w = f2bf(f.w);
    *(ushort4*)(dbf + i) = o;
    int p = __builtin_amdgcn_cvt_pk_fp8_f32(f.x, f.y, 0, 0);
    p = __builtin_amdgcn_cvt_pk_fp8_f32(f.z, f.w, p, 1);
    *(unsigned int*)(d8 + i) = p;
  }
}

// src f32 [K][N] row-major  ->  dst bf16 [N][K] row-major (transposed)
__global__ __launch_bounds__(256) void transpose_convert_kernel(
    const float* __restrict__ src, unsigned short* __restrict__ dst,
    int K, int N) {
  __shared__ unsigned short T[64 * 72];
  int kb = blockIdx.y * 64, nb = blockIdx.x * 64;
  int t = threadIdx.x;
  for (int u = t; u < 1024; u += 256) {
    int r = u >> 4, s = u & 15;
    float4 f = *(const float4*)(src + (size_t)(kb + r) * N + nb + s * 4);
    ushort4 o;
    o.x = f2bf(f.x); o.y = f2bf(f.y); o.z = f2bf(f.z); o.w = f2bf(f.w);
    *(ushort4*)&T[r * 72 + s * 4] = o;
  }
  __syncthreads();
  for (int u = t; u < 1024; u += 256) {
    int orow = u >> 4, s = u & 15;
    ushort4 o;
    o.x = T[(s * 4 + 0) * 72 + orow];
    o.y = T[(s * 4 + 1) * 72 + orow];
    o.z = T[(s * 4 + 2) * 72 + orow];
    o.w = T[(s * 4 + 3) * 72 + orow];
    *(ushort4*)(dst + (size_t)(nb + orow) * K + kb + s * 4) = o;
  }
}

// src f32 [K][N] row-major -> dst fp8 e4m3 [N][K] (transposed)
__global__ __launch_bounds__(256) void transpose_convert_fp8_kernel(
    const float* __restrict__ src, unsigned char* __restrict__ dst,
    int K, int N) {
  __shared__ unsigned short T[64 * 72];
  int kb = blockIdx.y * 64, nb = blockIdx.x * 64;
  int t = threadIdx.x;
  for (int u = t; u < 1024; u += 256) {
    int r = u >> 4, s = u & 15;
    float4 f = *(const float4*)(src + (size_t)(kb + r) * N + nb + s * 4);
    ushort4 o;
    o.x = f2bf(f.x); o.y = f2bf(f.y); o.z = f2bf(f.z); o.w = f2bf(f.w);
    *(ushort4*)&T[r * 72 + s * 4] = o;
  }
  __syncthreads();
  for (int u = t; u < 1024; u += 256) {
    int orow = u >> 4, s = u & 15;
    float f0 = __uint_as_float((unsigned int)T[(s * 4 + 0) * 72 + orow] << 16);
    float f1 = __uint_as_float((unsigned int)T[(s * 4 + 1) * 72 + orow] << 16);
    float f2 = __uint_as_float((unsigned int)T[(s * 4 + 2) * 72 + orow] << 16);
    float f3 = __uint_as_float((unsigned int)T[(s * 4 + 3) * 72 + orow] << 16);
    int p = __builtin_amdgcn_cvt_pk_fp8_f32(f0, f1, 0, 0);
    p = __builtin_amdgcn_cvt_pk_fp8_f32(f2, f3, p, 1);
    *(unsigned int*)&dst[(size_t)(nb + orow) * K + kb + s * 4] = p;
  }
}

// V slice of QKV [8192 rows][cols 2560..3071] -> VTg [512][8192] bf16.
__global__ __launch_bounds__(256) void vtrans_kernel(
    const unsigned short* __restrict__ QKV, unsigned short* __restrict__ VTg) {
  int flat = blockIdx.x * 256 + threadIdx.x;
  int c = flat & 511;
  int s0 = (flat >> 9) * 8;
  unsigned short tmp[8];
  #pragma unroll
  for (int j = 0; j < 8; ++j)
    tmp[j] = QKV[(size_t)(s0 + j) * 3072 + 2560 + c];
  *(uint4*)&VTg[(size_t)c * 8192 + s0] = *(uint4*)tmp;
}

// ---------------------------- bf16 GEMM (V-proj) ---------------------------
// C[M,:] (ldc) = A[M,K] * BT[N,K]^T ; m97 structure, 128x128 tile, BK=32.

template <bool F32OUT>
__global__ __launch_bounds__(256) void gemm_bt_kernel(
    const unsigned short* __restrict__ A, const unsigned short* __restrict__ BT,
    void* __restrict__ Cp, int M, int ldc, int K) {
  __shared__ unsigned short As[128 * 32];
  __shared__ unsigned short Bs[128 * 32];
  int mb = blockIdx.y * 128, nb = blockIdx.x * 128;
  int tid = threadIdx.x;
  int lane = tid & 63, wv = tid >> 6;
  int wrow = wv >> 1, wcol = wv & 1;
  int lr = lane >> 2, ls = lane & 3;
  int fr = lane & 15, fg = lane >> 4;
  f32x4 acc[4][4] = {};
  for (int k0 = 0; k0 < K; k0 += 32) {
    __syncthreads();
    #pragma unroll
    for (int r = 0; r < 2; ++r) {
      int s = wv * 2 + r;
      async16(&As[s * 512], &A[(size_t)(mb + s * 16 + lr) * K + k0 + ls * 8]);
      async16(&Bs[s * 512], &BT[(size_t)(nb + s * 16 + lr) * K + k0 + ls * 8]);
    }
    __syncthreads();
    bf16x8 a[4], b[4];
    #pragma unroll
    for (int rt = 0; rt < 4; ++rt)
      a[rt] = *(const bf16x8*)&As[(wrow * 64 + rt * 16 + fr) * 32 + fg * 8];
    #pragma unroll
    for (int ct = 0; ct < 4; ++ct)
      b[ct] = *(const bf16x8*)&Bs[(wcol * 64 + ct * 16 + fr) * 32 + fg * 8];
    #pragma unroll
    for (int rt = 0; rt < 4; ++rt)
      #pragma unroll
      for (int ct = 0; ct < 4; ++ct)
        acc[rt][ct] = mfma16(a[rt], b[ct], acc[rt][ct]);
  }
  #pragma unroll
  for (int rt = 0; rt < 4; ++rt)
    #pragma unroll
    for (int ct = 0; ct < 4; ++ct)
      #pragma unroll
      for (int i = 0; i < 4; ++i) {
        int row = mb + wrow * 64 + rt * 16 + fg * 4 + i;
        int col = nb + wcol * 64 + ct * 16 + fr;
        if constexpr (F32OUT)
          ((float*)Cp)[(size_t)row * ldc + col] = acc[rt][ct][i];
        else
          ((unsigned short*)Cp)[(size_t)row * ldc + col] = f2bf(acc[rt][ct][i]);
      }
}

// ------------------- 8-phase 256x256 bf16 GEMM (O-proj) --------------------
// (unchanged from R4 — verified, dropped out of top-5)

__global__ __launch_bounds__(512, 2) void gemm8p_oproj_kernel(
    const unsigned short* __restrict__ A, const unsigned short* __restrict__ BT,
    float* __restrict__ C, int ldc, int K) {
  __shared__ unsigned char lds[131072];
  const int mb = blockIdx.y * 256, nb = blockIdx.x * 256;
  const int tid = threadIdx.x;
  const int lane = tid & 63, wv = tid >> 6;
  const int wm = wv >> 2, wn = wv & 3;       // 2 x 4 wave grid
  const int fr = lane & 15, fg = lane >> 4;
  const int xr = (fr & 4) ? 32 : 0;          // read-side swizzle XOR
  const int a_base = (wm * 128 + fr) * 128 + ((fg * 16) ^ xr);
  const int b_base = (wn * 64 + fr) * 128 + ((fg * 16) ^ xr);
  // staging: lane's pre-swizzled logical offset within its 1024B chunk
  const int lsw = (lane * 16) ^ (lane & 32);
  const int lrow = lsw >> 7, lcol = (lsw & 127) >> 1;
  const int NT = K >> 6;

  f32x4 acc[8][4] = {};
  bf16x8 aF[4][2], bF[2][2];

#define FENCE_ asm volatile("" ::: "memory")
#define BAR_ { FENCE_; __builtin_amdgcn_s_barrier(); FENCE_; }
#define LGKM0_ asm volatile("s_waitcnt lgkmcnt(0)" ::: "memory")
#define STAGE_A_(BUFI, T, HALF)                                              \
  { _Pragma("unroll")                                                        \
    for (int l = 0; l < 2; ++l) {                                            \
      int cc = wv * 2 + l;                                                   \
      int rb = (cc >> 3) * 128 + (HALF) * 64 + (cc & 7) * 8;                 \
      async16(lds + (BUFI) * 65536 + rb * 128,                               \
              A + (size_t)(mb + rb + lrow) * K + (T) * 64 + lcol);           \
    } }
#define STAGE_B_(BUFI, T, HALF)                                              \
  { _Pragma("unroll")                                                        \
    for (int l = 0; l < 2; ++l) {                                            \
      int cc = wv * 2 + l;                                                   \
      int rb = (cc >> 2) * 64 + (HALF) * 32 + (cc & 3) * 8;                  \
      async16(lds + (BUFI) * 65536 + 32768 + rb * 128,                       \
              BT + (size_t)(nb + rb + lrow) * K + (T) * 64 + lcol);          \
    } }
#define LOAD_A_(HALF)                                                        \
  { _Pragma("unroll")                                                        \
    for (int q = 0; q < 4; ++q)                                              \
      _Pragma("unroll")                                                      \
      for (int kk = 0; kk < 2; ++kk)                                         \
        aF[q][kk] =                                                          \
            *(const bf16x8*)&Ab_[a_base + ((HALF)*4 + q) * 2048 + kk * 64]; }
#define LOAD_B_(HALF)                                                        \
  { _Pragma("unroll")                                                        \
    for (int c2 = 0; c2 < 2; ++c2)                                           \
      _Pragma("unroll")                                                      \
      for (int kk = 0; kk < 2; ++kk)                                         \
        bF[c2][kk] =                                                         \
            *(const bf16x8*)&Bb_[b_base + ((HALF)*2 + c2) * 2048 + kk * 64]; }
#define MFMA_(RT0, CT0)                                                      \
  { __builtin_amdgcn_s_setprio(1);                                           \
    _Pragma("unroll")                                                        \
    for (int q = 0; q < 4; ++q)                                              \
      _Pragma("unroll")                                                      \
      for (int c2 = 0; c2 < 2; ++c2) {                                       \
        acc[(RT0) + q][(CT0) + c2] =                                         \
            mfma16(aF[q][0], bF[c2][0], acc[(RT0) + q][(CT0) + c2]);         \
        acc[(RT0) + q][(CT0) + c2] =                                         \
            mfma16(aF[q][1], bF[c2][1], acc[(RT0) + q][(CT0) + c2]);         \
      }                                                                      \
    __builtin_amdgcn_s_setprio(0); }

  // prologue: tile0 complete + tile1 {B-c0 half, A-r1 half}
  STAGE_A_(0, 0, 0); STAGE_A_(0, 0, 1); STAGE_B_(0, 0, 0); STAGE_B_(0, 0, 1);
  STAGE_B_(1, 1, 0); STAGE_A_(1, 1, 1);
  asm volatile("s_waitcnt vmcnt(4)" ::: "memory");   // tile0 landed
  BAR_;

  for (int t = 0; t < NT; ++t) {
    const int cur = t & 1, nxt = cur ^ 1;
    const unsigned char* Ab_ = lds + cur * 65536;
    const unsigned char* Bb_ = Ab_ + 32768;
    // ---- phase 1: quadrant r0 x c0 (12 ds_reads)
    LOAD_A_(0); LOAD_B_(0);
    if (t + 1 < NT) STAGE_A_(nxt, t + 1, 0);
    BAR_; LGKM0_;
    MFMA_(0, 0);
    BAR_;
    // ---- phase 2: quadrant r1 x c0 (8 ds_reads, bF reused)
    LOAD_A_(1);
    if (t + 1 < NT) STAGE_B_(nxt, t + 1, 1);
    BAR_; LGKM0_;
    MFMA_(4, 0);
    BAR_;
    // ---- phase 3: quadrant r1 x c1 (4 ds_reads, aF reused)
    LOAD_B_(1);
    if (t + 2 < NT) STAGE_B_(cur, t + 2, 0);
    BAR_; LGKM0_;
    MFMA_(4, 2);
    BAR_;
    // ---- phase 4: quadrant r0 x c1 (8 ds_reads, bF reused)
    LOAD_A_(0);
    if (t + 2 < NT) STAGE_A_(cur, t + 2, 1);
    BAR_; LGKM0_;
    MFMA_(0, 2);
    asm volatile("s_waitcnt vmcnt(4)" ::: "memory"); // tile t+1 landed
    BAR_;
  }

  #pragma unroll
  for (int rt = 0; rt < 8; ++rt)
    #pragma unroll
    for (int ct = 0; ct < 4; ++ct)
      #pragma unroll
      for (int i = 0; i < 4; ++i) {
        int row = mb + wm * 128 + rt * 16 + fg * 4 + i;
        int col = nb + wn * 64 + ct * 16 + fr;
        C[(size_t)row * ldc + col] = acc[rt][ct][i];
      }
#undef FENCE_
#undef BAR_
#undef LGKM0_
#undef STAGE_A_
#undef STAGE_B_
#undef LOAD_A_
#undef LOAD_B_
#undef MFMA_
}

// ---------------------------- fp8 GEMM (Q/K proj) --------------------------
// C bf16 = A8[M,K] * B8T[N,K]^T, unit-scale MX fp8, 16x16x128 MFMA, BK=128.

__global__ __launch_bounds__(256) void gemm_qk_fp8_kernel(
    const unsigned char* __restrict__ A8, const unsigned char* __restrict__ B8,
    unsigned short* __restrict__ C, int M, int ldc, int K) {
  __shared__ unsigned char As[128 * 144];
  __shared__ unsigned char Bs[128 * 144];
  int mb = blockIdx.y * 128, nb = blockIdx.x * 128;
  int tid = threadIdx.x;
  int lane = tid & 63, wv = tid >> 6;
  int wrow = wv >> 1, wcol = wv & 1;
  int fr = lane & 15, fg = lane >> 4;
  int srow = tid >> 1, shalf = (tid & 1) * 64;   // staging: 64B half-rows
  f32x4 acc[4][4] = {};
  for (int k0 = 0; k0 < K; k0 += 128) {
    __syncthreads();
    #pragma unroll
    for (int j = 0; j < 4; ++j) {
      *(uint4*)&As[srow * 144 + shalf + j * 16] =
          *(const uint4*)&A8[(size_t)(mb + srow) * K + k0 + shalf + j * 16];
      *(uint4*)&Bs[srow * 144 + shalf + j * 16] =
          *(const uint4*)&B8[(size_t)(nb + srow) * K + k0 + shalf + j * 16];
    }
    __syncthreads();
    v8i a[4], b[4];
    #pragma unroll
    for (int rt = 0; rt < 4; ++rt) {
      int off = (wrow * 64 + rt * 16 + fr) * 144 + fg * 32;
      ((uint4*)&a[rt])[0] = *(const uint4*)&As[off];
      ((uint4*)&a[rt])[1] = *(const uint4*)&As[off + 16];
    }
    #pragma unroll
    for (int ct = 0; ct < 4; ++ct) {
      int off = (wcol * 64 + ct * 16 + fr) * 144 + fg * 32;
      ((uint4*)&b[ct])[0] = *(const uint4*)&Bs[off];
      ((uint4*)&b[ct])[1] = *(const uint4*)&Bs[off + 16];
    }
    #pragma unroll
    for (int rt = 0; rt < 4; ++rt)
      #pragma unroll
      for (int ct = 0; ct < 4; ++ct)
        acc[rt][ct] = __builtin_amdgcn_mfma_scale_f32_16x16x128_f8f6f4(
            a[rt], b[ct], acc[rt][ct], 0, 0,
            0, 0x7F7F7F7F,   // A scales: e8m0 127 = 1.0
            0, 0x7F7F7F7F);  // B scales
  }
  #pragma unroll
  for (int rt = 0; rt < 4; ++rt)
    #pragma unroll
    for (int ct = 0; ct < 4; ++ct)
      #pragma unroll
      for (int i = 0; i < 4; ++i) {
        int row = mb + wrow * 64 + rt * 16 + fg * 4 + i;
        int col = nb + wcol * 64 + ct * 16 + fr;
        C[(size_t)row * ldc + col] = f2bf(acc[rt][ct][i]);
      }
}

// ----------------------------- attention -----------------------------------
// R7 structure: 8 waves x (4 heads x 2 q-halves); each wave owns 32 queries
// of one head. Swapped QK^T (A=K, B=Q) in 32x32x16 MFMA => score col = query
// = lane&31, softmax lane-local (verified R6). P -> bf16 via cvt_pk_bf16;
// PV A-fragments via v_permlane32_swap_b32 (verified R6).
// K/V staging: global_load_lds into double-buffered LINEAR tiles
// K[2][64][128], V[2][128][64] shorts. XOR swizzle on bytes:
//   LDS[row][c] = G[row][c ^ ((row&7)<<4)]   (staged via pre-swizzled src)
//   read at      LDS[row][colB ^ ((row&7)<<4)]
// => 8 consecutive lanes (8 rows, fixed col) hit 8 distinct 16B slots =
// all 32 banks: conflict-free b128 column-slice reads on both K and V.
// Stage for tile t+1 issued at iteration start; the iteration-end
// __syncthreads (implicit vmcnt(0)+lgkmcnt(0)) drains it — latency hidden
// under QK^T+softmax+PV. One barrier per tile, zero staging registers.

#define SCALE_L2E 0.0112710027f   // log2(e)/128

__global__ __launch_bounds__(512, 2) void attn_kernel(
    const unsigned short* __restrict__ QKV,
    const unsigned short* __restrict__ VTg,
    unsigned short* __restrict__ O) {
  __shared__ unsigned short KsL[2 * 64 * 128];    // 32 KB, linear+swizzled
  __shared__ unsigned short VTsL[2 * 128 * 64];   // 32 KB, linear+swizzled
  __shared__ float Ls[8 * 32];
  const int g = blockIdx.y;
  const int qs = blockIdx.x * 64;
  const int tid = threadIdx.x;
  const int lane = tid & 63, w = tid >> 6;
  const int l31 = lane & 31, hl2 = lane >> 5;
  const int hl = w & 3, qh = w >> 2;
  const int h = g * 4 + hl;
  const int kcol = 2048 + g * 128;
  const int qg = qs + qh * 32 + l31;   // this lane's query row

  // Q fragments (B-operand): col = query l31, k = kk*16 + hl2*8 + j
  bf16x8 qf[8];
  {
    const unsigned short* qrow = &QKV[(size_t)qg * 3072 + h * 128];
    #pragma unroll
    for (int kk = 0; kk < 8; ++kk)
      qf[kk] = *(const bf16x8*)&qrow[kk * 16 + hl2 * 8];
  }

  f32x16 o32[4] = {};     // dc: d = dc*32 + l31; row = (r&3)+8*(r>>2)+4*hl2
  float l_lane = 0.f;

  // staging geometry: per thread 2 K-issues + 2 V-issues, async16.
  // K issue it: row = it*32 + w*4 + (lane>>4), src col shorts =
  //   ((lane&15)*8) ^ ((row&7)<<3); wave-uniform LDS base + lane*16.
  // V issue it: row = it*64 + w*8 + (lane>>3), src col shorts =
  //   ((lane&7)*8) ^ ((row&7)<<3).
  const int kr_ = w * 4 + (lane >> 4), kc_ = (lane & 15) * 8;
  const int vr_ = w * 8 + (lane >> 3), vc_ = (lane & 7) * 8;

#define STAGE_TILE_(KB, BI)                                                   \
  { _Pragma("unroll")                                                         \
    for (int it = 0; it < 2; ++it) {                                          \
      int kr = it * 32 + kr_;                                                 \
      async16(&KsL[(BI) * 8192 + it * 4096 + w * 512],                        \
              &QKV[(size_t)((KB) + kr) * 3072 + kcol +                        \
                   (kc_ ^ ((kr & 7) << 3))]);                                 \
      int vr = it * 64 + vr_;                                                 \
      async16(&VTsL[(BI) * 8192 + it * 4096 + w * 512],                       \
              &VTg[(size_t)(g * 128 + vr) * 8192 + (KB) +                     \
                   (vc_ ^ ((vr & 7) << 3))]);                                 \
    } }

  const int kb0 = qs >= 512 ? qs - 512 : 0;

  STAGE_TILE_(kb0, 0);
  __syncthreads();   // drains vmcnt -> tile0 resident

  int cur = 0;
  for (int kb = kb0; kb <= qs; kb += 64) {
    const bool hasnext = (kb + 64 <= qs);
    if (hasnext) STAGE_TILE_(kb + 64, cur ^ 1);   // hidden under compute

    const unsigned short* Kc = &KsL[cur * 8192];
    const unsigned short* Vc = &VTsL[cur * 8192];

    // ---- QK^T: S^T[key][query], 2 key-tiles of 32 ----
    f32x16 s32[2] = {};
    __builtin_amdgcn_s_setprio(1);
    #pragma unroll
    for (int kt = 0; kt < 2; ++kt)
      #pragma unroll
      for (int kk = 0; kk < 8; ++kk) {
        int row = kt * 32 + l31;
        bf16x8 kf = *(const bf16x8*)
            &Kc[row * 128 + ((kk * 16 + hl2 * 8) ^ ((row & 7) << 3))];
        s32[kt] = mfma32(kf, qf[kk], s32[kt]);
      }
    __builtin_amdgcn_s_setprio(0);

    // ---- softmax in-register + pack to bf16 pairs ----
    const bool edge = (kb > qs - 64) || (kb < qs - 448);
    unsigned int u[2][4][2];
    #pragma unroll
    for (int kt = 0; kt < 2; ++kt) {
      float p[16];
      #pragma unroll
      for (int r = 0; r < 16; ++r) {
        float pv = exp2f(s32[kt][r] * SCALE_L2E);
        if (edge) {
          int kg = kb + kt * 32 + (r & 3) + 8 * (r >> 2) + 4 * hl2;
          if (kg > qg || kg < qg - 511) pv = 0.f;
        }
        l_lane += pv;
        p[r] = pv;
      }
      #pragma unroll
      for (int gr = 0; gr < 4; ++gr) {
        u[kt][gr][0] = cvtpk_bf16(p[4 * gr + 0], p[4 * gr + 1]);
        u[kt][gr][1] = cvtpk_bf16(p[4 * gr + 2], p[4 * gr + 3]);
      }
    }

    // ---- build PV A-fragments via permlane32_swap (R6-verified) ----
    bf16x8 af[4];
    #pragma unroll
    for (int kc = 0; kc < 4; ++kc) {
      const int kt = kc >> 1;
      const int gLo = 2 * (kc & 1), gHi = gLo + 1;
      unsigned int xa0 = u[kt][gLo][0], xb0 = u[kt][gHi][0];
      unsigned int xa1 = u[kt][gLo][1], xb1 = u[kt][gHi][1];
      asm volatile("v_permlane32_swap_b32 %0, %1" : "+v"(xa0), "+v"(xb0));
      asm volatile("v_permlane32_swap_b32 %0, %1" : "+v"(xa1), "+v"(xb1));
      u32x4 t;
      t[0] = xa0; t[1] = xa1; t[2] = xb0; t[3] = xb1;
      af[kc] = __builtin_bit_cast(bf16x8, t);
    }

    // ---- PV: o += P * V ----
    __builtin_amdgcn_s_setprio(1);
    #pragma unroll
    for (int dc = 0; dc < 4; ++dc)
      #pragma unroll
      for (int kc = 0; kc < 4; ++kc) {
        int row = dc * 32 + l31;
        bf16x8 vf = *(const bf16x8*)
            &Vc[row * 64 + ((kc * 16 + hl2 * 8) ^ ((row & 7) << 3))];
        o32[dc] = mfma32(af[kc], vf, o32[dc]);
      }
    __builtin_amdgcn_s_setprio(0);

    __syncthreads();   // drains stage(t+1) vmcnt + publishes; one barrier/tile
    cur ^= 1;
  }

  // ---- normalize + write ----
  l_lane += __shfl_xor(l_lane, 32);       // other half's key-subset
  float linv = 1.f / l_lane;
  Ls[w * 32 + l31] = linv;                // per-wave, both halves write same
  asm volatile("s_waitcnt lgkmcnt(0)" ::: "memory");
  float lr[16];
  #pragma unroll
  for (int r = 0; r < 16; ++r)
    lr[r] = Ls[w * 32 + (r & 3) + 8 * (r >> 2) + 4 * hl2];
  #pragma unroll
  for (int dc = 0; dc < 4; ++dc)
    #pragma unroll
    for (int r = 0; r < 16; ++r) {
      int row = qs + qh * 32 + (r & 3) + 8 * (r >> 2) + 4 * hl2;
      O[(size_t)row * 2048 + h * 128 + dc * 32 + l31] =
          f2bf(o32[dc][r] * lr[r]);
    }
#undef STAGE_TILE_
}

// ------------------------------ launcher -----------------------------------

extern "C" void kernel_launch(void* const* d_in, const int* in_sizes, int n_in,
                              void* d_out, int out_size, void* d_ws, size_t ws_size,
                              hipStream_t stream) {
  const float* h  = (const float*)d_in[0];
  const float* Wq = (const float*)d_in[1];
  const float* Wk = (const float*)d_in[2];
  const float* Wv = (const float*)d_in[3];
  const float* Wo = (const float*)d_in[4];
  float* out = (float*)d_out;
  char* ws = (char*)d_ws;
  const int S = 8192, D = 2048;
  const size_t MB = 1024 * 1024;

  // workspace (byte offsets), 101 MB peak, time-multiplexed:
  unsigned short* QKV = (unsigned short*)(ws);             // [8192][3072] bf16, 48 MB
  unsigned short* hbf = (unsigned short*)(ws + 48 * MB);   // [8192][2048] bf16, 32 MB
  unsigned short* Ab  = hbf;                               // attn out (hbf dead after V gemm)
  unsigned char*  h8  = (unsigned char*)(ws + 80 * MB);    // [8192][2048] fp8, 16 MB
  unsigned short* VTg = (unsigned short*)(ws + 80 * MB);   // [512][8192] bf16 (h8 dead)
  unsigned short* WoT = (unsigned short*)(ws + 88 * MB);   // [2048][2048] bf16 (h8 dead)
  unsigned char*  W8  = (unsigned char*)(ws + 96 * MB);    // [2560][2048] fp8, 5 MB
  unsigned short* WvT = (unsigned short*)(ws + 96 * MB);   // [512][2048] bf16 (W8 dead)

  convert_h_kernel<<<16384, 256, 0, stream>>>(h, hbf, h8, S * D);
  transpose_convert_fp8_kernel<<<dim3(32, 32), 256, 0, stream>>>(Wq, W8, D, 2048);
  transpose_convert_fp8_kernel<<<dim3(8, 32), 256, 0, stream>>>(
      Wk, W8 + (size_t)2048 * 2048, D, 512);
  gemm_qk_fp8_kernel<<<dim3(20, 64), 256, 0, stream>>>(h8, W8, QKV, S, 3072, D);

  transpose_convert_kernel<<<dim3(8, 32), 256, 0, stream>>>(Wv, WvT, D, 512);
  gemm_bt_kernel<false><<<dim3(4, 64), 256, 0, stream>>>(hbf, WvT, QKV + 2560, S, 3072, D);

  vtrans_kernel<<<2048, 256, 0, stream>>>(QKV, VTg);
  transpose_convert_kernel<<<dim3(32, 32), 256, 0, stream>>>(Wo, WoT, D, 2048);
  attn_kernel<<<dim3(128, 4), 512, 0, stream>>>(QKV, VTg, Ab);
  gemm8p_oproj_kernel<<<dim3(8, 32), 512, 0, stream>>>(Ab, WoT, out, 2048, 2048);
}

// Round 5
// 411.104 us; speedup vs baseline: 1.0856x; 1.0270x over previous
//
#include <hip/hip_runtime.h>

// ---------------------------------------------------------------------------
// Sliding-window GQA attention block.
// R8: fixes the O-proj 8-phase kernel's LDS swizzle. R7 counters showed
// 8.39M bank conflicts: the 1-bit XOR ((fr&4)?32:0) spreads column reads
// across only 4 of 8 16B-slots -> banks 0-15 only -> 2x min cycles per
// ds_read_b128. New swizzle (same family as the verified attn kernel):
//   LDS[row][cB] = G[row][cB ^ ((row&7)<<4)]  (bytes, bits 4-6)
// staged via pre-swizzled global source (global_load_lds writes linearly),
// read with the same XOR folded AFTER the kk*64 term (bit6 is a swizzle
// bit). 8 slots x 4 banks = all 32 banks, 8 dwords each = conflict-free.
// Also: bijective XCD-aware block remap (256 WGs, %8==0): XCD x owns
// m-rows [4x,4x+4) x all n -> 8-way A-panel L2 reuse (FETCH 135MB -> ~80).
// attn (R7 structure, verified) and all other kernels unchanged.
// ---------------------------------------------------------------------------

typedef __bf16 bf16x8 __attribute__((ext_vector_type(8)));
typedef float f32x4 __attribute__((ext_vector_type(4)));
typedef float f32x16 __attribute__((ext_vector_type(16)));
typedef int v8i __attribute__((ext_vector_type(8)));
typedef unsigned int u32x4 __attribute__((ext_vector_type(4)));

__device__ __forceinline__ unsigned short f2bf(float f) {
  unsigned int u = __float_as_uint(f);
  u += 0x7fffu + ((u >> 16) & 1u);   // RNE
  return (unsigned short)(u >> 16);
}

__device__ __forceinline__ f32x4 mfma16(bf16x8 a, bf16x8 b, f32x4 c) {
  return __builtin_amdgcn_mfma_f32_16x16x32_bf16(a, b, c, 0, 0, 0);
}

__device__ __forceinline__ f32x16 mfma32(bf16x8 a, bf16x8 b, f32x16 c) {
  return __builtin_amdgcn_mfma_f32_32x32x16_bf16(a, b, c, 0, 0, 0);
}

// pack two f32 -> two bf16 in one u32 (RNE); no builtin on gfx950 (m240)
__device__ __forceinline__ unsigned int cvtpk_bf16(float lo, float hi) {
  unsigned int r;
  asm volatile("v_cvt_pk_bf16_f32 %0, %1, %2" : "=v"(r) : "v"(lo), "v"(hi));
  return r;
}

// async global->LDS, 16B per lane, deposits at wave-uniform base + lane*16
__device__ __forceinline__ void async16(void* lds, const void* g) {
  __builtin_amdgcn_global_load_lds(
      (__attribute__((address_space(1))) unsigned int*)g,
      (__attribute__((address_space(3))) unsigned int*)lds, 16, 0, 0);
}

// --------------------------- conversion kernels ----------------------------

// hidden f32 -> bf16 (for V-proj) AND fp8 e4m3 (for QK-proj)
__global__ __launch_bounds__(256) void convert_h_kernel(
    const float* __restrict__ src, unsigned short* __restrict__ dbf,
    unsigned char* __restrict__ d8, int n) {
  int i = (blockIdx.x * 256 + threadIdx.x) * 4;
  if (i < n) {
    float4 f = *(const float4*)(src + i);
    ushort4 o;
    o.x = f2bf(f.x); o.y = f2bf(f.y); o.z = f2bf(f.z); o.w = f2bf(f.w);
    *(ushort4*)(dbf + i) = o;
    int p = __builtin_amdgcn_cvt_pk_fp8_f32(f.x, f.y, 0, 0);
    p = __builtin_amdgcn_cvt_pk_fp8_f32(f.z, f.w, p, 1);
    *(unsigned int*)(d8 + i) = p;
  }
}

// src f32 [K][N] row-major  ->  dst bf16 [N][K] row-major (transposed)
__global__ __launch_bounds__(256) void transpose_convert_kernel(
    const float* __restrict__ src, unsigned short* __restrict__ dst,
    int K, int N) {
  __shared__ unsigned short T[64 * 72];
  int kb = blockIdx.y * 64, nb = blockIdx.x * 64;
  int t = threadIdx.x;
  for (int u = t; u < 1024; u += 256) {
    int r = u >> 4, s = u & 15;
    float4 f = *(const float4*)(src + (size_t)(kb + r) * N + nb + s * 4);
    ushort4 o;
    o.x = f2bf(f.x); o.y = f2bf(f.y); o.z = f2bf(f.z); o.w = f2bf(f.w);
    *(ushort4*)&T[r * 72 + s * 4] = o;
  }
  __syncthreads();
  for (int u = t; u < 1024; u += 256) {
    int orow = u >> 4, s = u & 15;
    ushort4 o;
    o.x = T[(s * 4 + 0) * 72 + orow];
    o.y = T[(s * 4 + 1) * 72 + orow];
    o.z = T[(s * 4 + 2) * 72 + orow];
    o.w = T[(s * 4 + 3) * 72 + orow];
    *(ushort4*)(dst + (size_t)(nb + orow) * K + kb + s * 4) = o;
  }
}

// src f32 [K][N] row-major -> dst fp8 e4m3 [N][K] (transposed)
__global__ __launch_bounds__(256) void transpose_convert_fp8_kernel(
    const float* __restrict__ src, unsigned char* __restrict__ dst,
    int K, int N) {
  __shared__ unsigned short T[64 * 72];
  int kb = blockIdx.y * 64, nb = blockIdx.x * 64;
  int t = threadIdx.x;
  for (int u = t; u < 1024; u += 256) {
    int r = u >> 4, s = u & 15;
    float4 f = *(const float4*)(src + (size_t)(kb + r) * N + nb + s * 4);
    ushort4 o;
    o.x = f2bf(f.x); o.y = f2bf(f.y); o.z = f2bf(f.z); o.w = f2bf(f.w);
    *(ushort4*)&T[r * 72 + s * 4] = o;
  }
  __syncthreads();
  for (int u = t; u < 1024; u += 256) {
    int orow = u >> 4, s = u & 15;
    float f0 = __uint_as_float((unsigned int)T[(s * 4 + 0) * 72 + orow] << 16);
    float f1 = __uint_as_float((unsigned int)T[(s * 4 + 1) * 72 + orow] << 16);
    float f2 = __uint_as_float((unsigned int)T[(s * 4 + 2) * 72 + orow] << 16);
    float f3 = __uint_as_float((unsigned int)T[(s * 4 + 3) * 72 + orow] << 16);
    int p = __builtin_amdgcn_cvt_pk_fp8_f32(f0, f1, 0, 0);
    p = __builtin_amdgcn_cvt_pk_fp8_f32(f2, f3, p, 1);
    *(unsigned int*)&dst[(size_t)(nb + orow) * K + kb + s * 4] = p;
  }
}

// V slice of QKV [8192 rows][cols 2560..3071] -> VTg [512][8192] bf16.
__global__ __launch_bounds__(256) void vtrans_kernel(
    const unsigned short* __restrict__ QKV, unsigned short* __restrict__ VTg) {
  int flat = blockIdx.x * 256 + threadIdx.x;
  int c = flat & 511;
  int s0 = (flat >> 9) * 8;
  unsigned short tmp[8];
  #pragma unroll
  for (int j = 0; j < 8; ++j)
    tmp[j] = QKV[(size_t)(s0 + j) * 3072 + 2560 + c];
  *(uint4*)&VTg[(size_t)c * 8192 + s0] = *(uint4*)tmp;
}

// ---------------------------- bf16 GEMM (V-proj) ---------------------------
// C[M,:] (ldc) = A[M,K] * BT[N,K]^T ; m97 structure, 128x128 tile, BK=32.

template <bool F32OUT>
__global__ __launch_bounds__(256) void gemm_bt_kernel(
    const unsigned short* __restrict__ A, const unsigned short* __restrict__ BT,
    void* __restrict__ Cp, int M, int ldc, int K) {
  __shared__ unsigned short As[128 * 32];
  __shared__ unsigned short Bs[128 * 32];
  int mb = blockIdx.y * 128, nb = blockIdx.x * 128;
  int tid = threadIdx.x;
  int lane = tid & 63, wv = tid >> 6;
  int wrow = wv >> 1, wcol = wv & 1;
  int lr = lane >> 2, ls = lane & 3;
  int fr = lane & 15, fg = lane >> 4;
  f32x4 acc[4][4] = {};
  for (int k0 = 0; k0 < K; k0 += 32) {
    __syncthreads();
    #pragma unroll
    for (int r = 0; r < 2; ++r) {
      int s = wv * 2 + r;
      async16(&As[s * 512], &A[(size_t)(mb + s * 16 + lr) * K + k0 + ls * 8]);
      async16(&Bs[s * 512], &BT[(size_t)(nb + s * 16 + lr) * K + k0 + ls * 8]);
    }
    __syncthreads();
    bf16x8 a[4], b[4];
    #pragma unroll
    for (int rt = 0; rt < 4; ++rt)
      a[rt] = *(const bf16x8*)&As[(wrow * 64 + rt * 16 + fr) * 32 + fg * 8];
    #pragma unroll
    for (int ct = 0; ct < 4; ++ct)
      b[ct] = *(const bf16x8*)&Bs[(wcol * 64 + ct * 16 + fr) * 32 + fg * 8];
    #pragma unroll
    for (int rt = 0; rt < 4; ++rt)
      #pragma unroll
      for (int ct = 0; ct < 4; ++ct)
        acc[rt][ct] = mfma16(a[rt], b[ct], acc[rt][ct]);
  }
  #pragma unroll
  for (int rt = 0; rt < 4; ++rt)
    #pragma unroll
    for (int ct = 0; ct < 4; ++ct)
      #pragma unroll
      for (int i = 0; i < 4; ++i) {
        int row = mb + wrow * 64 + rt * 16 + fg * 4 + i;
        int col = nb + wcol * 64 + ct * 16 + fr;
        if constexpr (F32OUT)
          ((float*)Cp)[(size_t)row * ldc + col] = acc[rt][ct][i];
        else
          ((unsigned short*)Cp)[(size_t)row * ldc + col] = f2bf(acc[rt][ct][i]);
      }
}

// ------------------- 8-phase 256x256 bf16 GEMM (O-proj) --------------------
// C f32 [M][ldc] = A bf16 [M][K] * BT bf16 [N][K]^T.  Grid flat 256 WGs.
// R8 swizzle: LDS[row][cB ^ ((row&7)<<4)], row stride 128B.
// Stage source pre-swizzle per lane: byte = lane*16 ^ ((lane>>3 & 7)<<4)
// (chunk rows are 8-aligned, row-in-chunk = lane>>3). Read XOR applied to
// the FULL column (fg*16 | kk*64) since bit6 participates.
// XCD remap: flat = y*8+x; xcd=flat&7; pos=flat>>3; m=xcd*4+pos/8; n=pos%8.

__global__ __launch_bounds__(512, 2) void gemm8p_oproj_kernel(
    const unsigned short* __restrict__ A, const unsigned short* __restrict__ BT,
    float* __restrict__ C, int ldc, int K) {
  __shared__ unsigned char lds[131072];
  // bijective XCD-aware remap (256 WGs, 8 XCDs)
  const int flat = blockIdx.y * 8 + blockIdx.x;
  const int xcd = flat & 7, pos = flat >> 3;
  const int mb = (xcd * 4 + (pos >> 3)) * 256, nb = (pos & 7) * 256;
  const int tid = threadIdx.x;
  const int lane = tid & 63, wv = tid >> 6;
  const int wm = wv >> 2, wn = wv & 3;       // 2 x 4 wave grid
  const int fr = lane & 15, fg = lane >> 4;
  const int swz = (fr & 7) << 4;             // read-side swizzle XOR (bytes)
  const int a_row = (wm * 128 + fr) * 128;   // byte offset of row base
  const int b_row = (wn * 64 + fr) * 128;
  const int ac0 = (fg * 16) ^ swz, ac1 = ac0 ^ 64;   // kk=0 / kk=1 col bytes
  // staging: lane's pre-swizzled logical offset within its 1024B chunk
  const int lsw = (lane * 16) ^ (((lane >> 3) & 7) << 4);
  const int lrow = lane >> 3, lcol = (lsw & 127) >> 1;   // row, col (shorts)
  const int NT = K >> 6;

  f32x4 acc[8][4] = {};
  bf16x8 aF[4][2], bF[2][2];

#define FENCE_ asm volatile("" ::: "memory")
#define BAR_ { FENCE_; __builtin_amdgcn_s_barrier(); FENCE_; }
#define LGKM0_ asm volatile("s_waitcnt lgkmcnt(0)" ::: "memory")
#define STAGE_A_(BUFI, T, HALF)                                              \
  { _Pragma("unroll")                                                        \
    for (int l = 0; l < 2; ++l) {                                            \
      int cc = wv * 2 + l;                                                   \
      int rb = (cc >> 3) * 128 + (HALF) * 64 + (cc & 7) * 8;                 \
      async16(lds + (BUFI) * 65536 + rb * 128,                               \
              A + (size_t)(mb + rb + lrow) * K + (T) * 64 + lcol);           \
    } }
#define STAGE_B_(BUFI, T, HALF)                                              \
  { _Pragma("unroll")                                                        \
    for (int l = 0; l < 2; ++l) {                                            \
      int cc = wv * 2 + l;                                                   \
      int rb = (cc >> 2) * 64 + (HALF) * 32 + (cc & 3) * 8;                  \
      async16(lds + (BUFI) * 65536 + 32768 + rb * 128,                       \
              BT + (size_t)(nb + rb + lrow) * K + (T) * 64 + lcol);          \
    } }
#define LOAD_A_(HALF)                                                        \
  { _Pragma("unroll")                                                        \
    for (int q = 0; q < 4; ++q) {                                            \
      aF[q][0] = *(const bf16x8*)&Ab_[a_row + ((HALF)*4 + q) * 2048 + ac0];  \
      aF[q][1] = *(const bf16x8*)&Ab_[a_row + ((HALF)*4 + q) * 2048 + ac1];  \
    } }
#define LOAD_B_(HALF)                                                        \
  { _Pragma("unroll")                                                        \
    for (int c2 = 0; c2 < 2; ++c2) {                                         \
      bF[c2][0] = *(const bf16x8*)&Bb_[b_row + ((HALF)*2 + c2) * 2048 + ac0];\
      bF[c2][1] = *(const bf16x8*)&Bb_[b_row + ((HALF)*2 + c2) * 2048 + ac1];\
    } }
#define MFMA_(RT0, CT0)                                                      \
  { __builtin_amdgcn_s_setprio(1);                                           \
    _Pragma("unroll")                                                        \
    for (int q = 0; q < 4; ++q)                                              \
      _Pragma("unroll")                                                      \
      for (int c2 = 0; c2 < 2; ++c2) {                                       \
        acc[(RT0) + q][(CT0) + c2] =                                         \
            mfma16(aF[q][0], bF[c2][0], acc[(RT0) + q][(CT0) + c2]);         \
        acc[(RT0) + q][(CT0) + c2] =                                         \
            mfma16(aF[q][1], bF[c2][1], acc[(RT0) + q][(CT0) + c2]);         \
      }                                                                      \
    __builtin_amdgcn_s_setprio(0); }

  // prologue: tile0 complete + tile1 {B-c0 half, A-r1 half}
  STAGE_A_(0, 0, 0); STAGE_A_(0, 0, 1); STAGE_B_(0, 0, 0); STAGE_B_(0, 0, 1);
  STAGE_B_(1, 1, 0); STAGE_A_(1, 1, 1);
  asm volatile("s_waitcnt vmcnt(4)" ::: "memory");   // tile0 landed
  BAR_;

  for (int t = 0; t < NT; ++t) {
    const int cur = t & 1, nxt = cur ^ 1;
    const unsigned char* Ab_ = lds + cur * 65536;
    const unsigned char* Bb_ = Ab_ + 32768;
    // ---- phase 1: quadrant r0 x c0 (12 ds_reads)
    LOAD_A_(0); LOAD_B_(0);
    if (t + 1 < NT) STAGE_A_(nxt, t + 1, 0);
    BAR_; LGKM0_;
    MFMA_(0, 0);
    BAR_;
    // ---- phase 2: quadrant r1 x c0 (8 ds_reads, bF reused)
    LOAD_A_(1);
    if (t + 1 < NT) STAGE_B_(nxt, t + 1, 1);
    BAR_; LGKM0_;
    MFMA_(4, 0);
    BAR_;
    // ---- phase 3: quadrant r1 x c1 (4 ds_reads, aF reused)
    LOAD_B_(1);
    if (t + 2 < NT) STAGE_B_(cur, t + 2, 0);
    BAR_; LGKM0_;
    MFMA_(4, 2);
    BAR_;
    // ---- phase 4: quadrant r0 x c1 (8 ds_reads, bF reused)
    LOAD_A_(0);
    if (t + 2 < NT) STAGE_A_(cur, t + 2, 1);
    BAR_; LGKM0_;
    MFMA_(0, 2);
    asm volatile("s_waitcnt vmcnt(4)" ::: "memory"); // tile t+1 landed
    BAR_;
  }

  #pragma unroll
  for (int rt = 0; rt < 8; ++rt)
    #pragma unroll
    for (int ct = 0; ct < 4; ++ct)
      #pragma unroll
      for (int i = 0; i < 4; ++i) {
        int row = mb + wm * 128 + rt * 16 + fg * 4 + i;
        int col = nb + wn * 64 + ct * 16 + fr;
        C[(size_t)row * ldc + col] = acc[rt][ct][i];
      }
#undef FENCE_
#undef BAR_
#undef LGKM0_
#undef STAGE_A_
#undef STAGE_B_
#undef LOAD_A_
#undef LOAD_B_
#undef MFMA_
}

// ---------------------------- fp8 GEMM (Q/K proj) --------------------------
// C bf16 = A8[M,K] * B8T[N,K]^T, unit-scale MX fp8, 16x16x128 MFMA, BK=128.

__global__ __launch_bounds__(256) void gemm_qk_fp8_kernel(
    const unsigned char* __restrict__ A8, const unsigned char* __restrict__ B8,
    unsigned short* __restrict__ C, int M, int ldc, int K) {
  __shared__ unsigned char As[128 * 144];
  __shared__ unsigned char Bs[128 * 144];
  int mb = blockIdx.y * 128, nb = blockIdx.x * 128;
  int tid = threadIdx.x;
  int lane = tid & 63, wv = tid >> 6;
  int wrow = wv >> 1, wcol = wv & 1;
  int fr = lane & 15, fg = lane >> 4;
  int srow = tid >> 1, shalf = (tid & 1) * 64;   // staging: 64B half-rows
  f32x4 acc[4][4] = {};
  for (int k0 = 0; k0 < K; k0 += 128) {
    __syncthreads();
    #pragma unroll
    for (int j = 0; j < 4; ++j) {
      *(uint4*)&As[srow * 144 + shalf + j * 16] =
          *(const uint4*)&A8[(size_t)(mb + srow) * K + k0 + shalf + j * 16];
      *(uint4*)&Bs[srow * 144 + shalf + j * 16] =
          *(const uint4*)&B8[(size_t)(nb + srow) * K + k0 + shalf + j * 16];
    }
    __syncthreads();
    v8i a[4], b[4];
    #pragma unroll
    for (int rt = 0; rt < 4; ++rt) {
      int off = (wrow * 64 + rt * 16 + fr) * 144 + fg * 32;
      ((uint4*)&a[rt])[0] = *(const uint4*)&As[off];
      ((uint4*)&a[rt])[1] = *(const uint4*)&As[off + 16];
    }
    #pragma unroll
    for (int ct = 0; ct < 4; ++ct) {
      int off = (wcol * 64 + ct * 16 + fr) * 144 + fg * 32;
      ((uint4*)&b[ct])[0] = *(const uint4*)&Bs[off];
      ((uint4*)&b[ct])[1] = *(const uint4*)&Bs[off + 16];
    }
    #pragma unroll
    for (int rt = 0; rt < 4; ++rt)
      #pragma unroll
      for (int ct = 0; ct < 4; ++ct)
        acc[rt][ct] = __builtin_amdgcn_mfma_scale_f32_16x16x128_f8f6f4(
            a[rt], b[ct], acc[rt][ct], 0, 0,
            0, 0x7F7F7F7F,   // A scales: e8m0 127 = 1.0
            0, 0x7F7F7F7F);  // B scales
  }
  #pragma unroll
  for (int rt = 0; rt < 4; ++rt)
    #pragma unroll
    for (int ct = 0; ct < 4; ++ct)
      #pragma unroll
      for (int i = 0; i < 4; ++i) {
        int row = mb + wrow * 64 + rt * 16 + fg * 4 + i;
        int col = nb + wcol * 64 + ct * 16 + fr;
        C[(size_t)row * ldc + col] = f2bf(acc[rt][ct][i]);
      }
}

// ----------------------------- attention -----------------------------------
// R7 structure (verified): 8 waves x (4 heads x 2 q-halves); swapped QK^T
// 32x32x16 (lane owns one query column), in-register softmax, cvt_pk_bf16 +
// permlane32_swap for PV A-fragments, global_load_lds double-buffered K/V
// with the (row&7)<<4 byte XOR swizzle on both sides.

#define SCALE_L2E 0.0112710027f   // log2(e)/128

__global__ __launch_bounds__(512, 2) void attn_kernel(
    const unsigned short* __restrict__ QKV,
    const unsigned short* __restrict__ VTg,
    unsigned short* __restrict__ O) {
  __shared__ unsigned short KsL[2 * 64 * 128];    // 32 KB, linear+swizzled
  __shared__ unsigned short VTsL[2 * 128 * 64];   // 32 KB, linear+swizzled
  __shared__ float Ls[8 * 32];
  const int g = blockIdx.y;
  const int qs = blockIdx.x * 64;
  const int tid = threadIdx.x;
  const int lane = tid & 63, w = tid >> 6;
  const int l31 = lane & 31, hl2 = lane >> 5;
  const int hl = w & 3, qh = w >> 2;
  const int h = g * 4 + hl;
  const int kcol = 2048 + g * 128;
  const int qg = qs + qh * 32 + l31;   // this lane's query row

  // Q fragments (B-operand): col = query l31, k = kk*16 + hl2*8 + j
  bf16x8 qf[8];
  {
    const unsigned short* qrow = &QKV[(size_t)qg * 3072 + h * 128];
    #pragma unroll
    for (int kk = 0; kk < 8; ++kk)
      qf[kk] = *(const bf16x8*)&qrow[kk * 16 + hl2 * 8];
  }

  f32x16 o32[4] = {};     // dc: d = dc*32 + l31; row = (r&3)+8*(r>>2)+4*hl2
  float l_lane = 0.f;

  const int kr_ = w * 4 + (lane >> 4), kc_ = (lane & 15) * 8;
  const int vr_ = w * 8 + (lane >> 3), vc_ = (lane & 7) * 8;

#define STAGE_TILE_(KB, BI)                                                   \
  { _Pragma("unroll")                                                         \
    for (int it = 0; it < 2; ++it) {                                          \
      int kr = it * 32 + kr_;                                                 \
      async16(&KsL[(BI) * 8192 + it * 4096 + w * 512],                        \
              &QKV[(size_t)((KB) + kr) * 3072 + kcol +                        \
                   (kc_ ^ ((kr & 7) << 3))]);                                 \
      int vr = it * 64 + vr_;                                                 \
      async16(&VTsL[(BI) * 8192 + it * 4096 + w * 512],                       \
              &VTg[(size_t)(g * 128 + vr) * 8192 + (KB) +                     \
                   (vc_ ^ ((vr & 7) << 3))]);                                 \
    } }

  const int kb0 = qs >= 512 ? qs - 512 : 0;

  STAGE_TILE_(kb0, 0);
  __syncthreads();   // drains vmcnt -> tile0 resident

  int cur = 0;
  for (int kb = kb0; kb <= qs; kb += 64) {
    const bool hasnext = (kb + 64 <= qs);
    if (hasnext) STAGE_TILE_(kb + 64, cur ^ 1);   // hidden under compute

    const unsigned short* Kc = &KsL[cur * 8192];
    const unsigned short* Vc = &VTsL[cur * 8192];

    // ---- QK^T: S^T[key][query], 2 key-tiles of 32 ----
    f32x16 s32[2] = {};
    __builtin_amdgcn_s_setprio(1);
    #pragma unroll
    for (int kt = 0; kt < 2; ++kt)
      #pragma unroll
      for (int kk = 0; kk < 8; ++kk) {
        int row = kt * 32 + l31;
        bf16x8 kf = *(const bf16x8*)
            &Kc[row * 128 + ((kk * 16 + hl2 * 8) ^ ((row & 7) << 3))];
        s32[kt] = mfma32(kf, qf[kk], s32[kt]);
      }
    __builtin_amdgcn_s_setprio(0);

    // ---- softmax in-register + pack to bf16 pairs ----
    const bool edge = (kb > qs - 64) || (kb < qs - 448);
    unsigned int u[2][4][2];
    #pragma unroll
    for (int kt = 0; kt < 2; ++kt) {
      float p[16];
      #pragma unroll
      for (int r = 0; r < 16; ++r) {
        float pv = exp2f(s32[kt][r] * SCALE_L2E);
        if (edge) {
          int kg = kb + kt * 32 + (r & 3) + 8 * (r >> 2) + 4 * hl2;
          if (kg > qg || kg < qg - 511) pv = 0.f;
        }
        l_lane += pv;
        p[r] = pv;
      }
      #pragma unroll
      for (int gr = 0; gr < 4; ++gr) {
        u[kt][gr][0] = cvtpk_bf16(p[4 * gr + 0], p[4 * gr + 1]);
        u[kt][gr][1] = cvtpk_bf16(p[4 * gr + 2], p[4 * gr + 3]);
      }
    }

    // ---- build PV A-fragments via permlane32_swap (R6-verified) ----
    bf16x8 af[4];
    #pragma unroll
    for (int kc = 0; kc < 4; ++kc) {
      const int kt = kc >> 1;
      const int gLo = 2 * (kc & 1), gHi = gLo + 1;
      unsigned int xa0 = u[kt][gLo][0], xb0 = u[kt][gHi][0];
      unsigned int xa1 = u[kt][gLo][1], xb1 = u[kt][gHi][1];
      asm volatile("v_permlane32_swap_b32 %0, %1" : "+v"(xa0), "+v"(xb0));
      asm volatile("v_permlane32_swap_b32 %0, %1" : "+v"(xa1), "+v"(xb1));
      u32x4 t;
      t[0] = xa0; t[1] = xa1; t[2] = xb0; t[3] = xb1;
      af[kc] = __builtin_bit_cast(bf16x8, t);
    }

    // ---- PV: o += P * V ----
    __builtin_amdgcn_s_setprio(1);
    #pragma unroll
    for (int dc = 0; dc < 4; ++dc)
      #pragma unroll
      for (int kc = 0; kc < 4; ++kc) {
        int row = dc * 32 + l31;
        bf16x8 vf = *(const bf16x8*)
            &Vc[row * 64 + ((kc * 16 + hl2 * 8) ^ ((row & 7) << 3))];
        o32[dc] = mfma32(af[kc], vf, o32[dc]);
      }
    __builtin_amdgcn_s_setprio(0);

    __syncthreads();   // drains stage(t+1) vmcnt + publishes; one barrier/tile
    cur ^= 1;
  }

  // ---- normalize + write ----
  l_lane += __shfl_xor(l_lane, 32);       // other half's key-subset
  float linv = 1.f / l_lane;
  Ls[w * 32 + l31] = linv;                // per-wave, both halves write same
  asm volatile("s_waitcnt lgkmcnt(0)" ::: "memory");
  float lr[16];
  #pragma unroll
  for (int r = 0; r < 16; ++r)
    lr[r] = Ls[w * 32 + (r & 3) + 8 * (r >> 2) + 4 * hl2];
  #pragma unroll
  for (int dc = 0; dc < 4; ++dc)
    #pragma unroll
    for (int r = 0; r < 16; ++r) {
      int row = qs + qh * 32 + (r & 3) + 8 * (r >> 2) + 4 * hl2;
      O[(size_t)row * 2048 + h * 128 + dc * 32 + l31] =
          f2bf(o32[dc][r] * lr[r]);
    }
#undef STAGE_TILE_
}

// ------------------------------ launcher -----------------------------------

extern "C" void kernel_launch(void* const* d_in, const int* in_sizes, int n_in,
                              void* d_out, int out_size, void* d_ws, size_t ws_size,
                              hipStream_t stream) {
  const float* h  = (const float*)d_in[0];
  const float* Wq = (const float*)d_in[1];
  const float* Wk = (const float*)d_in[2];
  const float* Wv = (const float*)d_in[3];
  const float* Wo = (const float*)d_in[4];
  float* out = (float*)d_out;
  char* ws = (char*)d_ws;
  const int S = 8192, D = 2048;
  const size_t MB = 1024 * 1024;

  // workspace (byte offsets), 101 MB peak, time-multiplexed:
  unsigned short* QKV = (unsigned short*)(ws);             // [8192][3072] bf16, 48 MB
  unsigned short* hbf = (unsigned short*)(ws + 48 * MB);   // [8192][2048] bf16, 32 MB
  unsigned short* Ab  = hbf;                               // attn out (hbf dead after V gemm)
  unsigned char*  h8  = (unsigned char*)(ws + 80 * MB);    // [8192][2048] fp8, 16 MB
  unsigned short* VTg = (unsigned short*)(ws + 80 * MB);   // [512][8192] bf16 (h8 dead)
  unsigned short* WoT = (unsigned short*)(ws + 88 * MB);   // [2048][2048] bf16 (h8 dead)
  unsigned char*  W8  = (unsigned char*)(ws + 96 * MB);    // [2560][2048] fp8, 5 MB
  unsigned short* WvT = (unsigned short*)(ws + 96 * MB);   // [512][2048] bf16 (W8 dead)

  convert_h_kernel<<<16384, 256, 0, stream>>>(h, hbf, h8, S * D);
  transpose_convert_fp8_kernel<<<dim3(32, 32), 256, 0, stream>>>(Wq, W8, D, 2048);
  transpose_convert_fp8_kernel<<<dim3(8, 32), 256, 0, stream>>>(
      Wk, W8 + (size_t)2048 * 2048, D, 512);
  gemm_qk_fp8_kernel<<<dim3(20, 64), 256, 0, stream>>>(h8, W8, QKV, S, 3072, D);

  transpose_convert_kernel<<<dim3(8, 32), 256, 0, stream>>>(Wv, WvT, D, 512);
  gemm_bt_kernel<false><<<dim3(4, 64), 256, 0, stream>>>(hbf, WvT, QKV + 2560, S, 3072, D);

  vtrans_kernel<<<2048, 256, 0, stream>>>(QKV, VTg);
  transpose_convert_kernel<<<dim3(32, 32), 256, 0, stream>>>(Wo, WoT, D, 2048);
  attn_kernel<<<dim3(128, 4), 512, 0, stream>>>(QKV, VTg, Ab);
  gemm8p_oproj_kernel<<<dim3(8, 32), 512, 0, stream>>>(Ab, WoT, out, 2048, 2048);
}

// Round 6
// 406.635 us; speedup vs baseline: 1.0975x; 1.0110x over previous
//
#include <hip/hip_runtime.h>

// ---------------------------------------------------------------------------
// Sliding-window GQA attention block.
// R9: XCD-locality round (T1), index remaps only — no kernel-body changes.
// attn: FETCH 87.6MB vs 16MB unique K/V (5.5x over-fetch) because adjacent
// qs-blocks (sharing 7/8 of their K-window) round-robin across XCDs. New
// flat-512 grid: xcd=b&7 owns 64 CONSECUTIVE q-blocks of one head-group;
// per-XCD K/V working set 2.36MB < 4MB L2 -> K/V fetched ~once from HBM.
// qk_fp8: same idea, flat-1280 grid, XCD owns 8-m-block chunk (2MB A-panel
// L2-resident), n-major order reuses each B-panel 8x back-to-back.
// Everything else identical to R8 (all verified).
// ---------------------------------------------------------------------------

typedef __bf16 bf16x8 __attribute__((ext_vector_type(8)));
typedef float f32x4 __attribute__((ext_vector_type(4)));
typedef float f32x16 __attribute__((ext_vector_type(16)));
typedef int v8i __attribute__((ext_vector_type(8)));
typedef unsigned int u32x4 __attribute__((ext_vector_type(4)));

__device__ __forceinline__ unsigned short f2bf(float f) {
  unsigned int u = __float_as_uint(f);
  u += 0x7fffu + ((u >> 16) & 1u);   // RNE
  return (unsigned short)(u >> 16);
}

__device__ __forceinline__ f32x4 mfma16(bf16x8 a, bf16x8 b, f32x4 c) {
  return __builtin_amdgcn_mfma_f32_16x16x32_bf16(a, b, c, 0, 0, 0);
}

__device__ __forceinline__ f32x16 mfma32(bf16x8 a, bf16x8 b, f32x16 c) {
  return __builtin_amdgcn_mfma_f32_32x32x16_bf16(a, b, c, 0, 0, 0);
}

// pack two f32 -> two bf16 in one u32 (RNE); no builtin on gfx950 (m240)
__device__ __forceinline__ unsigned int cvtpk_bf16(float lo, float hi) {
  unsigned int r;
  asm volatile("v_cvt_pk_bf16_f32 %0, %1, %2" : "=v"(r) : "v"(lo), "v"(hi));
  return r;
}

// async global->LDS, 16B per lane, deposits at wave-uniform base + lane*16
__device__ __forceinline__ void async16(void* lds, const void* g) {
  __builtin_amdgcn_global_load_lds(
      (__attribute__((address_space(1))) unsigned int*)g,
      (__attribute__((address_space(3))) unsigned int*)lds, 16, 0, 0);
}

// --------------------------- conversion kernels ----------------------------

// hidden f32 -> bf16 (for V-proj) AND fp8 e4m3 (for QK-proj)
__global__ __launch_bounds__(256) void convert_h_kernel(
    const float* __restrict__ src, unsigned short* __restrict__ dbf,
    unsigned char* __restrict__ d8, int n) {
  int i = (blockIdx.x * 256 + threadIdx.x) * 4;
  if (i < n) {
    float4 f = *(const float4*)(src + i);
    ushort4 o;
    o.x = f2bf(f.x); o.y = f2bf(f.y); o.z = f2bf(f.z); o.w = f2bf(f.w);
    *(ushort4*)(dbf + i) = o;
    int p = __builtin_amdgcn_cvt_pk_fp8_f32(f.x, f.y, 0, 0);
    p = __builtin_amdgcn_cvt_pk_fp8_f32(f.z, f.w, p, 1);
    *(unsigned int*)(d8 + i) = p;
  }
}

// src f32 [K][N] row-major  ->  dst bf16 [N][K] row-major (transposed)
__global__ __launch_bounds__(256) void transpose_convert_kernel(
    const float* __restrict__ src, unsigned short* __restrict__ dst,
    int K, int N) {
  __shared__ unsigned short T[64 * 72];
  int kb = blockIdx.y * 64, nb = blockIdx.x * 64;
  int t = threadIdx.x;
  for (int u = t; u < 1024; u += 256) {
    int r = u >> 4, s = u & 15;
    float4 f = *(const float4*)(src + (size_t)(kb + r) * N + nb + s * 4);
    ushort4 o;
    o.x = f2bf(f.x); o.y = f2bf(f.y); o.z = f2bf(f.z); o.w = f2bf(f.w);
    *(ushort4*)&T[r * 72 + s * 4] = o;
  }
  __syncthreads();
  for (int u = t; u < 1024; u += 256) {
    int orow = u >> 4, s = u & 15;
    ushort4 o;
    o.x = T[(s * 4 + 0) * 72 + orow];
    o.y = T[(s * 4 + 1) * 72 + orow];
    o.z = T[(s * 4 + 2) * 72 + orow];
    o.w = T[(s * 4 + 3) * 72 + orow];
    *(ushort4*)(dst + (size_t)(nb + orow) * K + kb + s * 4) = o;
  }
}

// src f32 [K][N] row-major -> dst fp8 e4m3 [N][K] (transposed)
__global__ __launch_bounds__(256) void transpose_convert_fp8_kernel(
    const float* __restrict__ src, unsigned char* __restrict__ dst,
    int K, int N) {
  __shared__ unsigned short T[64 * 72];
  int kb = blockIdx.y * 64, nb = blockIdx.x * 64;
  int t = threadIdx.x;
  for (int u = t; u < 1024; u += 256) {
    int r = u >> 4, s = u & 15;
    float4 f = *(const float4*)(src + (size_t)(kb + r) * N + nb + s * 4);
    ushort4 o;
    o.x = f2bf(f.x); o.y = f2bf(f.y); o.z = f2bf(f.z); o.w = f2bf(f.w);
    *(ushort4*)&T[r * 72 + s * 4] = o;
  }
  __syncthreads();
  for (int u = t; u < 1024; u += 256) {
    int orow = u >> 4, s = u & 15;
    float f0 = __uint_as_float((unsigned int)T[(s * 4 + 0) * 72 + orow] << 16);
    float f1 = __uint_as_float((unsigned int)T[(s * 4 + 1) * 72 + orow] << 16);
    float f2 = __uint_as_float((unsigned int)T[(s * 4 + 2) * 72 + orow] << 16);
    float f3 = __uint_as_float((unsigned int)T[(s * 4 + 3) * 72 + orow] << 16);
    int p = __builtin_amdgcn_cvt_pk_fp8_f32(f0, f1, 0, 0);
    p = __builtin_amdgcn_cvt_pk_fp8_f32(f2, f3, p, 1);
    *(unsigned int*)&dst[(size_t)(nb + orow) * K + kb + s * 4] = p;
  }
}

// V slice of QKV [8192 rows][cols 2560..3071] -> VTg [512][8192] bf16.
__global__ __launch_bounds__(256) void vtrans_kernel(
    const unsigned short* __restrict__ QKV, unsigned short* __restrict__ VTg) {
  int flat = blockIdx.x * 256 + threadIdx.x;
  int c = flat & 511;
  int s0 = (flat >> 9) * 8;
  unsigned short tmp[8];
  #pragma unroll
  for (int j = 0; j < 8; ++j)
    tmp[j] = QKV[(size_t)(s0 + j) * 3072 + 2560 + c];
  *(uint4*)&VTg[(size_t)c * 8192 + s0] = *(uint4*)tmp;
}

// ---------------------------- bf16 GEMM (V-proj) ---------------------------
// C[M,:] (ldc) = A[M,K] * BT[N,K]^T ; m97 structure, 128x128 tile, BK=32.

template <bool F32OUT>
__global__ __launch_bounds__(256) void gemm_bt_kernel(
    const unsigned short* __restrict__ A, const unsigned short* __restrict__ BT,
    void* __restrict__ Cp, int M, int ldc, int K) {
  __shared__ unsigned short As[128 * 32];
  __shared__ unsigned short Bs[128 * 32];
  int mb = blockIdx.y * 128, nb = blockIdx.x * 128;
  int tid = threadIdx.x;
  int lane = tid & 63, wv = tid >> 6;
  int wrow = wv >> 1, wcol = wv & 1;
  int lr = lane >> 2, ls = lane & 3;
  int fr = lane & 15, fg = lane >> 4;
  f32x4 acc[4][4] = {};
  for (int k0 = 0; k0 < K; k0 += 32) {
    __syncthreads();
    #pragma unroll
    for (int r = 0; r < 2; ++r) {
      int s = wv * 2 + r;
      async16(&As[s * 512], &A[(size_t)(mb + s * 16 + lr) * K + k0 + ls * 8]);
      async16(&Bs[s * 512], &BT[(size_t)(nb + s * 16 + lr) * K + k0 + ls * 8]);
    }
    __syncthreads();
    bf16x8 a[4], b[4];
    #pragma unroll
    for (int rt = 0; rt < 4; ++rt)
      a[rt] = *(const bf16x8*)&As[(wrow * 64 + rt * 16 + fr) * 32 + fg * 8];
    #pragma unroll
    for (int ct = 0; ct < 4; ++ct)
      b[ct] = *(const bf16x8*)&Bs[(wcol * 64 + ct * 16 + fr) * 32 + fg * 8];
    #pragma unroll
    for (int rt = 0; rt < 4; ++rt)
      #pragma unroll
      for (int ct = 0; ct < 4; ++ct)
        acc[rt][ct] = mfma16(a[rt], b[ct], acc[rt][ct]);
  }
  #pragma unroll
  for (int rt = 0; rt < 4; ++rt)
    #pragma unroll
    for (int ct = 0; ct < 4; ++ct)
      #pragma unroll
      for (int i = 0; i < 4; ++i) {
        int row = mb + wrow * 64 + rt * 16 + fg * 4 + i;
        int col = nb + wcol * 64 + ct * 16 + fr;
        if constexpr (F32OUT)
          ((float*)Cp)[(size_t)row * ldc + col] = acc[rt][ct][i];
        else
          ((unsigned short*)Cp)[(size_t)row * ldc + col] = f2bf(acc[rt][ct][i]);
      }
}

// ------------------- 8-phase 256x256 bf16 GEMM (O-proj) --------------------
// (R8-verified: conflict-free swizzle + XCD remap)

__global__ __launch_bounds__(512, 2) void gemm8p_oproj_kernel(
    const unsigned short* __restrict__ A, const unsigned short* __restrict__ BT,
    float* __restrict__ C, int ldc, int K) {
  __shared__ unsigned char lds[131072];
  // bijective XCD-aware remap (256 WGs, 8 XCDs)
  const int flat = blockIdx.y * 8 + blockIdx.x;
  const int xcd = flat & 7, pos = flat >> 3;
  const int mb = (xcd * 4 + (pos >> 3)) * 256, nb = (pos & 7) * 256;
  const int tid = threadIdx.x;
  const int lane = tid & 63, wv = tid >> 6;
  const int wm = wv >> 2, wn = wv & 3;       // 2 x 4 wave grid
  const int fr = lane & 15, fg = lane >> 4;
  const int swz = (fr & 7) << 4;             // read-side swizzle XOR (bytes)
  const int a_row = (wm * 128 + fr) * 128;   // byte offset of row base
  const int b_row = (wn * 64 + fr) * 128;
  const int ac0 = (fg * 16) ^ swz, ac1 = ac0 ^ 64;   // kk=0 / kk=1 col bytes
  // staging: lane's pre-swizzled logical offset within its 1024B chunk
  const int lsw = (lane * 16) ^ (((lane >> 3) & 7) << 4);
  const int lrow = lane >> 3, lcol = (lsw & 127) >> 1;   // row, col (shorts)
  const int NT = K >> 6;

  f32x4 acc[8][4] = {};
  bf16x8 aF[4][2], bF[2][2];

#define FENCE_ asm volatile("" ::: "memory")
#define BAR_ { FENCE_; __builtin_amdgcn_s_barrier(); FENCE_; }
#define LGKM0_ asm volatile("s_waitcnt lgkmcnt(0)" ::: "memory")
#define STAGE_A_(BUFI, T, HALF)                                              \
  { _Pragma("unroll")                                                        \
    for (int l = 0; l < 2; ++l) {                                            \
      int cc = wv * 2 + l;                                                   \
      int rb = (cc >> 3) * 128 + (HALF) * 64 + (cc & 7) * 8;                 \
      async16(lds + (BUFI) * 65536 + rb * 128,                               \
              A + (size_t)(mb + rb + lrow) * K + (T) * 64 + lcol);           \
    } }
#define STAGE_B_(BUFI, T, HALF)                                              \
  { _Pragma("unroll")                                                        \
    for (int l = 0; l < 2; ++l) {                                            \
      int cc = wv * 2 + l;                                                   \
      int rb = (cc >> 2) * 64 + (HALF) * 32 + (cc & 3) * 8;                  \
      async16(lds + (BUFI) * 65536 + 32768 + rb * 128,                       \
              BT + (size_t)(nb + rb + lrow) * K + (T) * 64 + lcol);          \
    } }
#define LOAD_A_(HALF)                                                        \
  { _Pragma("unroll")                                                        \
    for (int q = 0; q < 4; ++q) {                                            \
      aF[q][0] = *(const bf16x8*)&Ab_[a_row + ((HALF)*4 + q) * 2048 + ac0];  \
      aF[q][1] = *(const bf16x8*)&Ab_[a_row + ((HALF)*4 + q) * 2048 + ac1];  \
    } }
#define LOAD_B_(HALF)                                                        \
  { _Pragma("unroll")                                                        \
    for (int c2 = 0; c2 < 2; ++c2) {                                         \
      bF[c2][0] = *(const bf16x8*)&Bb_[b_row + ((HALF)*2 + c2) * 2048 + ac0];\
      bF[c2][1] = *(const bf16x8*)&Bb_[b_row + ((HALF)*2 + c2) * 2048 + ac1];\
    } }
#define MFMA_(RT0, CT0)                                                      \
  { __builtin_amdgcn_s_setprio(1);                                           \
    _Pragma("unroll")                                                        \
    for (int q = 0; q < 4; ++q)                                              \
      _Pragma("unroll")                                                      \
      for (int c2 = 0; c2 < 2; ++c2) {                                       \
        acc[(RT0) + q][(CT0) + c2] =                                         \
            mfma16(aF[q][0], bF[c2][0], acc[(RT0) + q][(CT0) + c2]);         \
        acc[(RT0) + q][(CT0) + c2] =                                         \
            mfma16(aF[q][1], bF[c2][1], acc[(RT0) + q][(CT0) + c2]);         \
      }                                                                      \
    __builtin_amdgcn_s_setprio(0); }

  // prologue: tile0 complete + tile1 {B-c0 half, A-r1 half}
  STAGE_A_(0, 0, 0); STAGE_A_(0, 0, 1); STAGE_B_(0, 0, 0); STAGE_B_(0, 0, 1);
  STAGE_B_(1, 1, 0); STAGE_A_(1, 1, 1);
  asm volatile("s_waitcnt vmcnt(4)" ::: "memory");   // tile0 landed
  BAR_;

  for (int t = 0; t < NT; ++t) {
    const int cur = t & 1, nxt = cur ^ 1;
    const unsigned char* Ab_ = lds + cur * 65536;
    const unsigned char* Bb_ = Ab_ + 32768;
    // ---- phase 1: quadrant r0 x c0 (12 ds_reads)
    LOAD_A_(0); LOAD_B_(0);
    if (t + 1 < NT) STAGE_A_(nxt, t + 1, 0);
    BAR_; LGKM0_;
    MFMA_(0, 0);
    BAR_;
    // ---- phase 2: quadrant r1 x c0 (8 ds_reads, bF reused)
    LOAD_A_(1);
    if (t + 1 < NT) STAGE_B_(nxt, t + 1, 1);
    BAR_; LGKM0_;
    MFMA_(4, 0);
    BAR_;
    // ---- phase 3: quadrant r1 x c1 (4 ds_reads, aF reused)
    LOAD_B_(1);
    if (t + 2 < NT) STAGE_B_(cur, t + 2, 0);
    BAR_; LGKM0_;
    MFMA_(4, 2);
    BAR_;
    // ---- phase 4: quadrant r0 x c1 (8 ds_reads, bF reused)
    LOAD_A_(0);
    if (t + 2 < NT) STAGE_A_(cur, t + 2, 1);
    BAR_; LGKM0_;
    MFMA_(0, 2);
    asm volatile("s_waitcnt vmcnt(4)" ::: "memory"); // tile t+1 landed
    BAR_;
  }

  #pragma unroll
  for (int rt = 0; rt < 8; ++rt)
    #pragma unroll
    for (int ct = 0; ct < 4; ++ct)
      #pragma unroll
      for (int i = 0; i < 4; ++i) {
        int row = mb + wm * 128 + rt * 16 + fg * 4 + i;
        int col = nb + wn * 64 + ct * 16 + fr;
        C[(size_t)row * ldc + col] = acc[rt][ct][i];
      }
#undef FENCE_
#undef BAR_
#undef LGKM0_
#undef STAGE_A_
#undef STAGE_B_
#undef LOAD_A_
#undef LOAD_B_
#undef MFMA_
}

// ---------------------------- fp8 GEMM (Q/K proj) --------------------------
// C bf16 = A8[M,K] * B8T[N,K]^T, unit-scale MX fp8, 16x16x128 MFMA, BK=128.
// R9: flat 1280-WG grid with XCD remap: xcd owns m-chunk [8*xcd, 8*xcd+8),
// n-major order within XCD (A-panel 2MB L2-resident; B-panel reused 8x).

__global__ __launch_bounds__(256) void gemm_qk_fp8_kernel(
    const unsigned char* __restrict__ A8, const unsigned char* __restrict__ B8,
    unsigned short* __restrict__ C, int M, int ldc, int K) {
  __shared__ unsigned char As[128 * 144];
  __shared__ unsigned char Bs[128 * 144];
  const int f = blockIdx.x;
  const int xcd = f & 7, pos = f >> 3;           // 160 blocks per XCD
  const int mb = (xcd * 8 + (pos & 7)) * 128;    // m-chunk local
  const int nb = (pos >> 3) * 128;               // n-major sweep
  int tid = threadIdx.x;
  int lane = tid & 63, wv = tid >> 6;
  int wrow = wv >> 1, wcol = wv & 1;
  int fr = lane & 15, fg = lane >> 4;
  int srow = tid >> 1, shalf = (tid & 1) * 64;   // staging: 64B half-rows
  f32x4 acc[4][4] = {};
  for (int k0 = 0; k0 < K; k0 += 128) {
    __syncthreads();
    #pragma unroll
    for (int j = 0; j < 4; ++j) {
      *(uint4*)&As[srow * 144 + shalf + j * 16] =
          *(const uint4*)&A8[(size_t)(mb + srow) * K + k0 + shalf + j * 16];
      *(uint4*)&Bs[srow * 144 + shalf + j * 16] =
          *(const uint4*)&B8[(size_t)(nb + srow) * K + k0 + shalf + j * 16];
    }
    __syncthreads();
    v8i a[4], b[4];
    #pragma unroll
    for (int rt = 0; rt < 4; ++rt) {
      int off = (wrow * 64 + rt * 16 + fr) * 144 + fg * 32;
      ((uint4*)&a[rt])[0] = *(const uint4*)&As[off];
      ((uint4*)&a[rt])[1] = *(const uint4*)&As[off + 16];
    }
    #pragma unroll
    for (int ct = 0; ct < 4; ++ct) {
      int off = (wcol * 64 + ct * 16 + fr) * 144 + fg * 32;
      ((uint4*)&b[ct])[0] = *(const uint4*)&Bs[off];
      ((uint4*)&b[ct])[1] = *(const uint4*)&Bs[off + 16];
    }
    #pragma unroll
    for (int rt = 0; rt < 4; ++rt)
      #pragma unroll
      for (int ct = 0; ct < 4; ++ct)
        acc[rt][ct] = __builtin_amdgcn_mfma_scale_f32_16x16x128_f8f6f4(
            a[rt], b[ct], acc[rt][ct], 0, 0,
            0, 0x7F7F7F7F,   // A scales: e8m0 127 = 1.0
            0, 0x7F7F7F7F);  // B scales
  }
  #pragma unroll
  for (int rt = 0; rt < 4; ++rt)
    #pragma unroll
    for (int ct = 0; ct < 4; ++ct)
      #pragma unroll
      for (int i = 0; i < 4; ++i) {
        int row = mb + wrow * 64 + rt * 16 + fg * 4 + i;
        int col = nb + wcol * 64 + ct * 16 + fr;
        C[(size_t)row * ldc + col] = f2bf(acc[rt][ct][i]);
      }
}

// ----------------------------- attention -----------------------------------
// R7/R8 body (verified). R9: flat 512-WG grid, XCD-aware decomposition:
// xcd = b&7 owns head-group g = xcd>>1 and 64 CONSECUTIVE q-blocks
// (qs_idx = (xcd&1)*64 + (b>>3)) -> per-XCD K/V working set 2.36MB < L2.

#define SCALE_L2E 0.0112710027f   // log2(e)/128

__global__ __launch_bounds__(512, 2) void attn_kernel(
    const unsigned short* __restrict__ QKV,
    const unsigned short* __restrict__ VTg,
    unsigned short* __restrict__ O) {
  __shared__ unsigned short KsL[2 * 64 * 128];    // 32 KB, linear+swizzled
  __shared__ unsigned short VTsL[2 * 128 * 64];   // 32 KB, linear+swizzled
  __shared__ float Ls[8 * 32];
  const int b = blockIdx.x;                 // 0..511, dispatch xcd = b&7
  const int xcd = b & 7, idx = b >> 3;
  const int g = xcd >> 1;                   // 2 XCDs per head-group
  const int qs = ((xcd & 1) * 64 + idx) * 64;
  const int tid = threadIdx.x;
  const int lane = tid & 63, w = tid >> 6;
  const int l31 = lane & 31, hl2 = lane >> 5;
  const int hl = w & 3, qh = w >> 2;
  const int h = g * 4 + hl;
  const int kcol = 2048 + g * 128;
  const int qg = qs + qh * 32 + l31;   // this lane's query row

  // Q fragments (B-operand): col = query l31, k = kk*16 + hl2*8 + j
  bf16x8 qf[8];
  {
    const unsigned short* qrow = &QKV[(size_t)qg * 3072 + h * 128];
    #pragma unroll
    for (int kk = 0; kk < 8; ++kk)
      qf[kk] = *(const bf16x8*)&qrow[kk * 16 + hl2 * 8];
  }

  f32x16 o32[4] = {};     // dc: d = dc*32 + l31; row = (r&3)+8*(r>>2)+4*hl2
  float l_lane = 0.f;

  const int kr_ = w * 4 + (lane >> 4), kc_ = (lane & 15) * 8;
  const int vr_ = w * 8 + (lane >> 3), vc_ = (lane & 7) * 8;

#define STAGE_TILE_(KB, BI)                                                   \
  { _Pragma("unroll")                                                         \
    for (int it = 0; it < 2; ++it) {                                          \
      int kr = it * 32 + kr_;                                                 \
      async16(&KsL[(BI) * 8192 + it * 4096 + w * 512],                        \
              &QKV[(size_t)((KB) + kr) * 3072 + kcol +                        \
                   (kc_ ^ ((kr & 7) << 3))]);                                 \
      int vr = it * 64 + vr_;                                                 \
      async16(&VTsL[(BI) * 8192 + it * 4096 + w * 512],                       \
              &VTg[(size_t)(g * 128 + vr) * 8192 + (KB) +                     \
                   (vc_ ^ ((vr & 7) << 3))]);                                 \
    } }

  const int kb0 = qs >= 512 ? qs - 512 : 0;

  STAGE_TILE_(kb0, 0);
  __syncthreads();   // drains vmcnt -> tile0 resident

  int cur = 0;
  for (int kb = kb0; kb <= qs; kb += 64) {
    const bool hasnext = (kb + 64 <= qs);
    if (hasnext) STAGE_TILE_(kb + 64, cur ^ 1);   // hidden under compute

    const unsigned short* Kc = &KsL[cur * 8192];
    const unsigned short* Vc = &VTsL[cur * 8192];

    // ---- QK^T: S^T[key][query], 2 key-tiles of 32 ----
    f32x16 s32[2] = {};
    __builtin_amdgcn_s_setprio(1);
    #pragma unroll
    for (int kt = 0; kt < 2; ++kt)
      #pragma unroll
      for (int kk = 0; kk < 8; ++kk) {
        int row = kt * 32 + l31;
        bf16x8 kf = *(const bf16x8*)
            &Kc[row * 128 + ((kk * 16 + hl2 * 8) ^ ((row & 7) << 3))];
        s32[kt] = mfma32(kf, qf[kk], s32[kt]);
      }
    __builtin_amdgcn_s_setprio(0);

    // ---- softmax in-register + pack to bf16 pairs ----
    const bool edge = (kb > qs - 64) || (kb < qs - 448);
    unsigned int u[2][4][2];
    #pragma unroll
    for (int kt = 0; kt < 2; ++kt) {
      float p[16];
      #pragma unroll
      for (int r = 0; r < 16; ++r) {
        float pv = exp2f(s32[kt][r] * SCALE_L2E);
        if (edge) {
          int kg = kb + kt * 32 + (r & 3) + 8 * (r >> 2) + 4 * hl2;
          if (kg > qg || kg < qg - 511) pv = 0.f;
        }
        l_lane += pv;
        p[r] = pv;
      }
      #pragma unroll
      for (int gr = 0; gr < 4; ++gr) {
        u[kt][gr][0] = cvtpk_bf16(p[4 * gr + 0], p[4 * gr + 1]);
        u[kt][gr][1] = cvtpk_bf16(p[4 * gr + 2], p[4 * gr + 3]);
      }
    }

    // ---- build PV A-fragments via permlane32_swap (R6-verified) ----
    bf16x8 af[4];
    #pragma unroll
    for (int kc = 0; kc < 4; ++kc) {
      const int kt = kc >> 1;
      const int gLo = 2 * (kc & 1), gHi = gLo + 1;
      unsigned int xa0 = u[kt][gLo][0], xb0 = u[kt][gHi][0];
      unsigned int xa1 = u[kt][gLo][1], xb1 = u[kt][gHi][1];
      asm volatile("v_permlane32_swap_b32 %0, %1" : "+v"(xa0), "+v"(xb0));
      asm volatile("v_permlane32_swap_b32 %0, %1" : "+v"(xa1), "+v"(xb1));
      u32x4 t;
      t[0] = xa0; t[1] = xa1; t[2] = xb0; t[3] = xb1;
      af[kc] = __builtin_bit_cast(bf16x8, t);
    }

    // ---- PV: o += P * V ----
    __builtin_amdgcn_s_setprio(1);
    #pragma unroll
    for (int dc = 0; dc < 4; ++dc)
      #pragma unroll
      for (int kc = 0; kc < 4; ++kc) {
        int row = dc * 32 + l31;
        bf16x8 vf = *(const bf16x8*)
            &Vc[row * 64 + ((kc * 16 + hl2 * 8) ^ ((row & 7) << 3))];
        o32[dc] = mfma32(af[kc], vf, o32[dc]);
      }
    __builtin_amdgcn_s_setprio(0);

    __syncthreads();   // drains stage(t+1) vmcnt + publishes; one barrier/tile
    cur ^= 1;
  }

  // ---- normalize + write ----
  l_lane += __shfl_xor(l_lane, 32);       // other half's key-subset
  float linv = 1.f / l_lane;
  Ls[w * 32 + l31] = linv;                // per-wave, both halves write same
  asm volatile("s_waitcnt lgkmcnt(0)" ::: "memory");
  float lr[16];
  #pragma unroll
  for (int r = 0; r < 16; ++r)
    lr[r] = Ls[w * 32 + (r & 3) + 8 * (r >> 2) + 4 * hl2];
  #pragma unroll
  for (int dc = 0; dc < 4; ++dc)
    #pragma unroll
    for (int r = 0; r < 16; ++r) {
      int row = qs + qh * 32 + (r & 3) + 8 * (r >> 2) + 4 * hl2;
      O[(size_t)row * 2048 + h * 128 + dc * 32 + l31] =
          f2bf(o32[dc][r] * lr[r]);
    }
#undef STAGE_TILE_
}

// ------------------------------ launcher -----------------------------------

extern "C" void kernel_launch(void* const* d_in, const int* in_sizes, int n_in,
                              void* d_out, int out_size, void* d_ws, size_t ws_size,
                              hipStream_t stream) {
  const float* h  = (const float*)d_in[0];
  const float* Wq = (const float*)d_in[1];
  const float* Wk = (const float*)d_in[2];
  const float* Wv = (const float*)d_in[3];
  const float* Wo = (const float*)d_in[4];
  float* out = (float*)d_out;
  char* ws = (char*)d_ws;
  const int S = 8192, D = 2048;
  const size_t MB = 1024 * 1024;

  // workspace (byte offsets), 101 MB peak, time-multiplexed:
  unsigned short* QKV = (unsigned short*)(ws);             // [8192][3072] bf16, 48 MB
  unsigned short* hbf = (unsigned short*)(ws + 48 * MB);   // [8192][2048] bf16, 32 MB
  unsigned short* Ab  = hbf;                               // attn out (hbf dead after V gemm)
  unsigned char*  h8  = (unsigned char*)(ws + 80 * MB);    // [8192][2048] fp8, 16 MB
  unsigned short* VTg = (unsigned short*)(ws + 80 * MB);   // [512][8192] bf16 (h8 dead)
  unsigned short* WoT = (unsigned short*)(ws + 88 * MB);   // [2048][2048] bf16 (h8 dead)
  unsigned char*  W8  = (unsigned char*)(ws + 96 * MB);    // [2560][2048] fp8, 5 MB
  unsigned short* WvT = (unsigned short*)(ws + 96 * MB);   // [512][2048] bf16 (W8 dead)

  convert_h_kernel<<<16384, 256, 0, stream>>>(h, hbf, h8, S * D);
  transpose_convert_fp8_kernel<<<dim3(32, 32), 256, 0, stream>>>(Wq, W8, D, 2048);
  transpose_convert_fp8_kernel<<<dim3(8, 32), 256, 0, stream>>>(
      Wk, W8 + (size_t)2048 * 2048, D, 512);
  gemm_qk_fp8_kernel<<<1280, 256, 0, stream>>>(h8, W8, QKV, S, 3072, D);

  transpose_convert_kernel<<<dim3(8, 32), 256, 0, stream>>>(Wv, WvT, D, 512);
  gemm_bt_kernel<false><<<dim3(4, 64), 256, 0, stream>>>(hbf, WvT, QKV + 2560, S, 3072, D);

  vtrans_kernel<<<2048, 256, 0, stream>>>(QKV, VTg);
  transpose_convert_kernel<<<dim3(32, 32), 256, 0, stream>>>(Wo, WoT, D, 2048);
  attn_kernel<<<512, 512, 0, stream>>>(QKV, VTg, Ab);
  gemm8p_oproj_kernel<<<dim3(8, 32), 512, 0, stream>>>(Ab, WoT, out, 2048, 2048);
}